// Round 4
// baseline (846.984 us; speedup 1.0000x reference)
//
#include <hip/hip_runtime.h>

typedef unsigned short u16;
typedef __attribute__((ext_vector_type(8))) short bf16x8;   // 8 bf16 (4 VGPRs)
typedef __attribute__((ext_vector_type(4))) float f32x4;

#define D_EMB 1024
#define NBAT  256
#define AS1 __attribute__((address_space(1)))
#define AS3 __attribute__((address_space(3)))

__device__ __forceinline__ u16 f2bf(float f){
    unsigned int u = __float_as_uint(f);
    unsigned int r = (u + 0x7fffu + ((u >> 16) & 1u)) >> 16;  // RNE
    return (u16)r;
}
__device__ __forceinline__ float leaky(float x){ return x > 0.f ? x : 0.1f * x; }

// truncation-pack two fp32 into 2 bf16 (memory order: a = low u16, b = high u16)
__device__ __forceinline__ unsigned pack2(float a, float b){
    return (__float_as_uint(a) >> 16) | (__float_as_uint(b) & 0xffff0000u);
}

// AGPR stash: park a u32 in the accumulator half of the unified RF.
// During the post-phase weight window the AGPR file is idle (GEMM acc dead,
// pacc not yet live), so 38 stashed words cost ZERO arch VGPRs -> the
// (256,5) 48-arch budget holds and the R2/R3 scratch spill (525/132 MB
// WRITE_SIZE) disappears. Indices are compile-time after unroll, so each
// element is its own AGPR-class vreg (no scratch, rule #20 safe).
__device__ __forceinline__ void ag_write(unsigned &a, unsigned v){
    asm volatile("v_accvgpr_write_b32 %0, %1" : "=a"(a) : "v"(v));
}
__device__ __forceinline__ unsigned ag_read(unsigned a){
    unsigned v;
    asm volatile("v_accvgpr_read_b32 %0, %1" : "=v"(v) : "a"(a));
    return v;
}

// ---------------------------------------------------------------------------
// Pack img_emb(+pool_img as row 36) and cap_emb(+pool_txt as row 40) to bf16.
// imgw: [256][37][1024] bf16, capw: [256][41][1024] bf16
// ---------------------------------------------------------------------------
__global__ void pack_kernel(const float* __restrict__ pool_img, const float* __restrict__ img_emb,
                            const float* __restrict__ pool_txt, const float* __restrict__ cap_emb,
                            u16* __restrict__ imgw, u16* __restrict__ capw){
    int row = blockIdx.x;            // 0..19967
    const float* src; u16* dst;
    if (row < NBAT * 37){
        int e = row / 37, rr = row - e * 37;
        src = (rr < 36) ? (img_emb + ((size_t)e * 36 + rr) * D_EMB) : (pool_img + (size_t)e * D_EMB);
        dst = imgw + (size_t)row * D_EMB;
    } else {
        int r2 = row - NBAT * 37;
        int e = r2 / 41, rr = r2 - e * 41;
        src = (rr < 40) ? (cap_emb + ((size_t)e * 40 + rr) * D_EMB) : (pool_txt + (size_t)e * D_EMB);
        dst = capw + (size_t)r2 * D_EMB;
    }
    int t = threadIdx.x;             // 256 threads, 4 floats each
    float4 v = ((const float4*)src)[t];
    unsigned long long pk = (unsigned long long)f2bf(v.x)
        | ((unsigned long long)f2bf(v.y) << 16)
        | ((unsigned long long)f2bf(v.z) << 32)
        | ((unsigned long long)f2bf(v.w) << 48);
    *(unsigned long long*)(dst + (size_t)t * 4) = pk;
}

// ---------------------------------------------------------------------------
// Pool-vector norms
// ---------------------------------------------------------------------------
__global__ void norm_kernel(const float* __restrict__ pool_img, const float* __restrict__ pool_txt,
                            float* __restrict__ w1i, float* __restrict__ w1t){
    __shared__ float red[256];
    int v = blockIdx.x;              // 0..511
    const float* src = (v < 256) ? (pool_img + (size_t)v * D_EMB)
                                 : (pool_txt + (size_t)(v - 256) * D_EMB);
    int t = threadIdx.x;
    float4 x = ((const float4*)src)[t];
    red[t] = x.x*x.x + x.y*x.y + x.z*x.z + x.w*x.w;
    __syncthreads();
    for (int off = 128; off > 0; off >>= 1){
        if (t < off) red[t] += red[t + off];
        __syncthreads();
    }
    if (t == 0){
        float n = sqrtf(red[0]);
        if (v < 256) w1i[v] = n; else w1t[v - 256] = n;
    }
}

// ---------------------------------------------------------------------------
// MFMA Gram kernel (reads packed bf16): blk<256 -> G[b]=E_img E_img^T (R=36),
// else H[b]=E_cap E_cap^T (R=40). Frag-order staging via global_load_lds.
// ---------------------------------------------------------------------------
__launch_bounds__(256, 2)
__global__ void gram_kernel(const u16* __restrict__ imgw, const u16* __restrict__ capw,
                            float* __restrict__ G, float* __restrict__ H){
    __shared__ __align__(16) char gsm[6144];    // 3 tiles x 2 kk x 64 lanes x 16B
    int blk = blockIdx.x;
    int tid = threadIdx.x, lane = tid & 63;
    int wave = __builtin_amdgcn_readfirstlane(tid >> 6);
    int frow = lane & 15, q = lane >> 4;

    const u16* E; float* Gout; int R;
    if (blk < NBAT){ E = imgw + (size_t)blk * 37 * D_EMB; Gout = G + (size_t)blk * 1296; R = 36; }
    else { int b = blk - NBAT; E = capw + (size_t)b * 41 * D_EMB; Gout = H + (size_t)b * 1600; R = 40; }

    {   // zero staging once (pad rows stay zero)
        uint4 z = {0u,0u,0u,0u};
        for (int off = tid * 16; off < 6144; off += 4096) *(uint4*)(gsm + off) = z;
    }

    // staging groups g = kk*3 + t, g in [0,6)
    const u16* gsrc[2]; int goff[2]; bool gval[2];
    #pragma unroll
    for (int j = 0; j < 2; ++j){
        int g = wave + j * 4;
        gval[j] = false; gsrc[j] = E; goff[j] = 0;
        if (g < 6){
            int kk = g / 3, t = g - kk * 3;
            int row = t * 16 + frow;
            gsrc[j] = E + (size_t)row * D_EMB + kk * 32 + q * 8;
            goff[j] = g * 1024;
            gval[j] = (row < R);
        }
    }

    int wm = wave >> 1, wn = wave & 1;
    int nTm = wm ? 1 : 2, nTn = wn ? 1 : 2;
    f32x4 acc[2][2];
    #pragma unroll
    for (int a = 0; a < 2; ++a)
        #pragma unroll
        for (int b = 0; b < 2; ++b) acc[a][b] = (f32x4){0.f,0.f,0.f,0.f};

    for (int c = 0; c < 16; ++c){
        __syncthreads();
        #pragma unroll
        for (int j = 0; j < 2; ++j){
            if (gval[j]){
                __builtin_amdgcn_global_load_lds(
                    (const AS1 void*)(const void*)(gsrc[j] + c * 64),
                    (AS3 void*)(void*)(gsm + goff[j] + lane * 16),
                    16, 0, 0);
            }
        }
        __syncthreads();
        #pragma unroll
        for (int kk = 0; kk < 2; ++kk){
            bf16x8 fA[2], fB[2];
            #pragma unroll
            for (int mi = 0; mi < 2; ++mi)
                if (mi < nTm) fA[mi] = *(const bf16x8*)(gsm + ((kk * 3 + (wm + mi * 2)) * 64 + lane) * 16);
            #pragma unroll
            for (int ni = 0; ni < 2; ++ni)
                if (ni < nTn) fB[ni] = *(const bf16x8*)(gsm + ((kk * 3 + (wn + ni * 2)) * 64 + lane) * 16);
            #pragma unroll
            for (int mi = 0; mi < 2; ++mi)
                if (mi < nTm)
                    #pragma unroll
                    for (int ni = 0; ni < 2; ++ni)
                        if (ni < nTn)
                            acc[mi][ni] = __builtin_amdgcn_mfma_f32_16x16x32_bf16(
                                fA[mi], fB[ni], acc[mi][ni], 0, 0, 0);
        }
    }

    #pragma unroll
    for (int mi = 0; mi < 2; ++mi){
        if (mi < nTm){
            int tm = wm + mi * 2;
            #pragma unroll
            for (int ni = 0; ni < 2; ++ni){
                if (ni < nTn){
                    int tn = wn + ni * 2;
                    int col = tn * 16 + frow;
                    if (col < R){
                        #pragma unroll
                        for (int g = 0; g < 4; ++g){
                            int row = tm * 16 + q * 4 + g;
                            if (row < R) Gout[row * R + col] = acc[mi][ni][g];
                        }
                    }
                }
            }
        }
    }
}

// ---------------------------------------------------------------------------
// Cholesky kernel: per matrix, G = L·L^T (fp32), store L^T rows as bf16 in
// [48][64] zero-padded layout: Lb[n][k] = L[k][n]. One wave per matrix.
// ---------------------------------------------------------------------------
template<int R>
__device__ __forceinline__ void chol_wave(const float* __restrict__ src,
                                          u16* __restrict__ dst, int lane){
    int r = lane;
    bool act = (r < R);
    const float* row = src + (size_t)(act ? r : 0) * R;
    float a[R];
    #pragma unroll
    for (int k = 0; k < R; ++k) a[k] = act ? row[k] : 0.f;
    #pragma unroll
    for (int j = 0; j < R; ++j){
        float ajj = __shfl(a[j], j);
        float inv = (ajj > 1e-12f) ? rsqrtf(ajj) : 0.f;
        float lrj = a[j] * inv;
        if (r < j || !act) lrj = 0.f;           // strict lower + diag only
        dst[j * 64 + lane] = f2bf(lrj);         // row j of Lb = column j of L
        #pragma unroll
        for (int k = j + 1; k < R; ++k){
            float lkj = __shfl(lrj, k);
            a[k] = fmaf(-lrj, lkj, a[k]);
        }
    }
    #pragma unroll
    for (int j = R; j < 48; ++j) dst[j * 64 + lane] = 0;   // zero pad rows
}

__global__ void chol_kernel(const float* __restrict__ G, const float* __restrict__ H,
                            u16* __restrict__ Lbi, u16* __restrict__ Lbc){
    int lane = threadIdx.x & 63;
    int wave = threadIdx.x >> 6;
    int id = blockIdx.x * 4 + wave;   // 0..511 (uniform branch per block)
    if (id < NBAT) chol_wave<36>(G + (size_t)id * 1296, Lbi + (size_t)id * 3072, lane);
    else           chol_wave<40>(H + (size_t)(id - NBAT) * 1600, Lbc + (size_t)(id - NBAT) * 3072, lane);
}

// ---------------------------------------------------------------------------
// Fused main kernel. One block = 2 images x 2 captions.
// GEMM phase: double-buffered K=32 chunks, prefetch-then-compute, 1 barrier
// per chunk (loads overlap ds_read+MFMA; barrier's vmcnt(0) drain is covered).
// Post phase: u^T G u / v^T H v via per-wave MFMA against Cholesky factors.
// REGISTER DISCIPLINE for (256,5) = 48 arch + 48 AGPR split: R3 still spilled
// 132 MB because up[18]+vp[20]+scalars exceed 48 arch at the staging point
// (both matrices must exist before either staging write overlays Call).
// FIX: park the packed weight words in AGPRs (ag_write/ag_read) -- the AGPR
// file is idle in that window (GEMM acc dead, pacc unborn). 38 stash AGPRs
// <= 48 budget; arch peak drops to ~25.
// ---------------------------------------------------------------------------
__launch_bounds__(256, 5)
__global__ void fused_kernel(const u16* __restrict__ imgw, const u16* __restrict__ capw,
                             const u16* __restrict__ Lbi, const u16* __restrict__ Lbc,
                             const float* __restrict__ w1i, const float* __restrict__ w1t,
                             float* __restrict__ out){
    __shared__ __align__(16) char smem[26624];
    float* Call = (float*)smem;                 // overlay after GEMM: [74][85]
    float* rnb  = (float*)(smem + 25160);       // [4][36]
    float* cnb  = (float*)(smem + 25736);       // [4][40]

    int tid  = threadIdx.x;
    int lane = tid & 63;
    int wave = __builtin_amdgcn_readfirstlane(tid >> 6);
    int frow = lane & 15, q = lane >> 4;

    int lin = blockIdx.x;
    int xcd = lin & 7;                   // XCD-aware swizzle (16384 % 8 == 0, bijective)
    int s   = lin >> 3;                  // 0..2047
    int b_t = (xcd << 4) | (s & 15);     // each XCD owns 16 b-tiles
    int i_t = s >> 4;                    // 0..127
    int b0 = b_t * 2, i0 = i_t * 2;
    const u16* Ag = imgw + (size_t)b0 * 37 * D_EMB;   // 74 rows
    const u16* Bg = capw + (size_t)i0 * 41 * D_EMB;   // 82 rows

    {   // zero staging region once (pad slots stay zero forever)
        uint4 z = {0u,0u,0u,0u};
        for (int off = tid * 16; off < 22528; off += 4096) *(uint4*)(smem + off) = z;
    }

    // staging groups per K=32 chunk: 11 groups (A tiles 0..4, B tiles 5..10);
    // wave w handles g in {w, w+4, w+8}. Per-chunk buffer: A at g*1024,
    // B at 5120 + gb*1024; buffer base alternates 0 / 11264.
    const u16* gsrc[3]; int goff[3]; bool gval[3];
    #pragma unroll
    for (int j = 0; j < 3; ++j){
        int g = wave + j * 4;
        gval[j] = false; gsrc[j] = Ag; goff[j] = 0;
        if (g < 11){
            if (g < 5){
                int row = g * 16 + frow;
                gsrc[j] = Ag + (size_t)row * D_EMB + q * 8;
                goff[j] = g * 1024;
                gval[j] = (row < 74);
            } else {
                int gb = g - 5;
                int row = gb * 16 + frow;
                gsrc[j] = Bg + (size_t)row * D_EMB + q * 8;
                goff[j] = 5120 + gb * 1024;
                gval[j] = (row < 82);
            }
        }
    }

    int wm = wave >> 1, wn = wave & 1;     // 2x2 wave grid over 5x6 MFMA tiles
    int nTm = wm ? 2 : 3;                  // m-tiles {wm, wm+2, wm+4} < 5
    f32x4 acc[3][3];
    #pragma unroll
    for (int aa = 0; aa < 3; ++aa)
        #pragma unroll
        for (int bb = 0; bb < 3; ++bb) acc[aa][bb] = (f32x4){0.f, 0.f, 0.f, 0.f};

    __syncthreads();                       // zero-init visible before staging

    // prologue: stage chunk 0 into buffer 0
    #pragma unroll
    for (int j = 0; j < 3; ++j){
        if (gval[j]){
            __builtin_amdgcn_global_load_lds(
                (const AS1 void*)(const void*)(gsrc[j]),
                (AS3 void*)(void*)(smem + goff[j] + lane * 16),
                16, 0, 0);
        }
    }
    __syncthreads();                       // chunk 0 landed

    for (int c = 0; c < 32; ++c){          // K chunks of 32
        if (c < 31){                       // issue NEXT chunk first (prefetch)
            int nb = ((c + 1) & 1) * 11264;
            #pragma unroll
            for (int j = 0; j < 3; ++j){
                if (gval[j]){
                    __builtin_amdgcn_global_load_lds(
                        (const AS1 void*)(const void*)(gsrc[j] + (c + 1) * 32),
                        (AS3 void*)(void*)(smem + nb + goff[j] + lane * 16),
                        16, 0, 0);
                }
            }
        }
        int cb = (c & 1) * 11264;          // compute CURRENT chunk under the loads
        bf16x8 bfr[3];
        #pragma unroll
        for (int ni = 0; ni < 3; ++ni){
            int tn = wn + ni * 2;
            bfr[ni] = *(const bf16x8*)(smem + cb + 5120 + tn * 1024 + lane * 16);
        }
        #pragma unroll
        for (int mi = 0; mi < 3; ++mi){
            if (mi < nTm){
                int tm = wm + mi * 2;
                bf16x8 af = *(const bf16x8*)(smem + cb + tm * 1024 + lane * 16);
                #pragma unroll
                for (int ni = 0; ni < 3; ++ni){
                    acc[mi][ni] = __builtin_amdgcn_mfma_f32_16x16x32_bf16(
                        af, bfr[ni], acc[mi][ni], 0, 0, 0);
                }
            }
        }
        __syncthreads();                   // drains prefetch (overlapped) + guards buffer swap
    }

    // C/D layout: col = lane&15 (B-row), row = (lane>>4)*4 + reg (A-row)
    #pragma unroll
    for (int mi = 0; mi < 3; ++mi){
        if (mi < nTm){
            int tm = wm + mi * 2;
            #pragma unroll
            for (int ni = 0; ni < 3; ++ni){
                int tn = wn + ni * 2;
                int col = tn * 16 + frow;
                int rbase = tm * 16 + q * 4;
                if (col < 82){
                    #pragma unroll
                    for (int g = 0; g < 4; ++g){
                        int rowc = rbase + g;
                        if (rowc < 74) Call[rowc * 85 + col] = acc[mi][ni][g];
                    }
                }
            }
        }
    }
    __syncthreads();

    // ----- post-processing: one wave per (b,i) pair -----
    int pb = wave >> 1, pi = wave & 1;
    int bg = b0 + pb, ig = i0 + pi;
    const float* Sv = Call + (pb * 37) * 85 + pi * 41;  // S[r*85+l]; p[r]=S[r*85+40]; qv[l]=S[36*85+l]
    const u16* Lb_t2i = Lbi + (size_t)bg * 3072;        // [48][64] bf16, B[n][k]=L[k][n]
    const u16* Lb_i2t = Lbc + (size_t)ig * 3072;

    {   // row norms over words (lanes = regions)
        int r0 = (lane < 36) ? lane : 35;
        float s2 = 0.f;
        #pragma unroll
        for (int l = 0; l < 40; ++l){ float x = leaky(Sv[r0 * 85 + l]); s2 = fmaf(x, x, s2); }
        if (lane < 36) rnb[wave * 36 + lane] = 1.f / (sqrtf(s2) + 1e-8f);
    }
    {   // column norms over regions (lanes = words)
        int l0 = (lane < 40) ? lane : 39;
        float s2 = 0.f;
        #pragma unroll
        for (int r = 0; r < 36; ++r){ float x = leaky(Sv[r * 85 + l0]); s2 = fmaf(x, x, s2); }
        if (lane < 40) cnb[wave * 40 + lane] = 1.f / (sqrtf(s2) + 1e-8f);
    }

    // softmax weights u (lanes = words) + t2i numerator (dd cancels in sim).
    // Packed pairs go straight to AGPR stash -> ~0 arch VGPR held.
    unsigned upa[18]; float num1 = 0.f;
    {
        int lc = (lane < 40) ? lane : 39;
        #pragma unroll
        for (int r = 0; r < 36; r += 2){
            float x0 = leaky(Sv[r * 85 + lc]) * rnb[wave * 36 + r];
            float x1 = leaky(Sv[(r + 1) * 85 + lc]) * rnb[wave * 36 + r + 1];
            float e0 = __expf(9.0f * x0), e1 = __expf(9.0f * x1);
            num1 = fmaf(e0, Sv[r * 85 + 40], fmaf(e1, Sv[(r + 1) * 85 + 40], num1));
            ag_write(upa[r >> 1], pack2(e0, e1));
        }
    }
    // softmax weights v (lanes = regions) + i2t numerator
    unsigned vpa[20]; float num2 = 0.f;
    {
        int rc = (lane < 36) ? lane : 35;
        #pragma unroll
        for (int l = 0; l < 40; l += 2){
            float x0 = leaky(Sv[rc * 85 + l]) * cnb[wave * 40 + l];
            float x1 = leaky(Sv[rc * 85 + l + 1]) * cnb[wave * 40 + l + 1];
            float e0 = __expf(9.0f * x0), e1 = __expf(9.0f * x1);
            num2 = fmaf(e0, Sv[36 * 85 + l], fmaf(e1, Sv[36 * 85 + l + 1], num2));
            ag_write(vpa[l >> 1], pack2(e0, e1));
        }
    }
    float base = Sv[36 * 85 + 40];
    __syncthreads();        // S fully consumed by ALL waves; Call -> frag staging

    // per-wave packed staging slice (6144 B): u-matrix rows 0..39 at stride
    // 80 B (slots 0..4 = cols 0..39), v-matrix at +3200, rows 0..35.
    // Both staged NOW (reading back from AGPR stash) so no weight array ever
    // occupies arch VGPRs. ds_read_b128 start bank = (20*row+4q)%32: rows
    // 0..7 tile all 32 banks within a 16-lane phase group, rows 8..15
    // repeat -> 2-way (free, m136).
    char* slice = smem + wave * 6144;

    if (lane < 40){                        // stage u: cols 0..35 data, 36..39 zero
        char* rp = slice + lane * 80;
        #pragma unroll
        for (int jj = 0; jj < 9; ++jj){
            uint2 w; w.x = ag_read(upa[jj * 2]); w.y = ag_read(upa[jj * 2 + 1]);
            *(uint2*)(rp + jj * 8) = w;
        }
        uint2 z2; z2.x = 0u; z2.y = 0u;
        *(uint2*)(rp + 72) = z2;
    }
    if (lane < 36){                        // stage v: cols 0..39 all data
        char* rp = slice + 3200 + lane * 80;
        #pragma unroll
        for (int jj = 0; jj < 10; ++jj){
            uint2 w; w.x = ag_read(vpa[jj * 2]); w.y = ag_read(vpa[jj * 2 + 1]);
            *(uint2*)(rp + jj * 8) = w;
        }
    }

    // ---- t2i:  Y = U·L_img  (M=40 words, N=36, K=36 pad 64) ----
    float tsum;
    {
        f32x4 pacc[3][3];
        #pragma unroll
        for (int aa = 0; aa < 3; ++aa)
            #pragma unroll
            for (int bb = 0; bb < 3; ++bb) pacc[aa][bb] = (f32x4){0.f,0.f,0.f,0.f};
        #pragma unroll
        for (int kk = 0; kk < 2; ++kk){
            bf16x8 afr[3];
            #pragma unroll
            for (int mt = 0; mt < 3; ++mt){
                int row = mt * 16 + frow;      // rows>=40 read adjacent finite LDS; masked below
                if (kk == 0){
                    afr[mt] = *(const bf16x8*)(slice + row * 80 + q * 16);
                } else {
                    bf16x8 z = (bf16x8){0,0,0,0,0,0,0,0};
                    if (q == 0) z = *(const bf16x8*)(slice + row * 80 + 64);  // k=32..39
                    afr[mt] = z;               // q>=1: k=40..63 pad -> zero
                }
            }
            #pragma unroll
            for (int nt = 0; nt < 3; ++nt){
                bf16x8 bfr = *(const bf16x8*)(Lb_t2i + (nt * 16 + frow) * 64 + kk * 32 + q * 8);
                #pragma unroll
                for (int mt = 0; mt < 3; ++mt)
                    pacc[mt][nt] = __builtin_amdgcn_mfma_f32_16x16x32_bf16(
                        afr[mt], bfr, pacc[mt][nt], 0, 0, 0);
            }
        }
        // zz[m] = sum_n Y[m][n]^2 ; D layout: (m = 16mt+4q+g, n = 16nt+frow)
        float w1 = w1t[ig];
        tsum = 0.f;
        #pragma unroll
        for (int mt = 0; mt < 3; ++mt){
            #pragma unroll
            for (int g = 0; g < 4; ++g){
                float sv = pacc[mt][0][g] * pacc[mt][0][g]
                         + pacc[mt][1][g] * pacc[mt][1][g];
                float t2 = pacc[mt][2][g] * pacc[mt][2][g];
                sv += (frow < 4) ? t2 : 0.f;            // n = 32+frow < 36
                sv += __shfl_xor(sv, 1); sv += __shfl_xor(sv, 2);
                sv += __shfl_xor(sv, 4); sv += __shfl_xor(sv, 8);
                int m = mt * 16 + 4 * q + g;
                float nm = __shfl(num1, m);
                float sim = nm / fmaxf(w1 * sqrtf(sv), 1e-8f);
                tsum += (m < 40) ? sim : 0.f;           // mask garbage words
            }
        }
        tsum += __shfl_xor(tsum, 16);
        tsum += __shfl_xor(tsum, 32);
    }

    // ---- i2t:  Y = V·L_cap  (M=36 regions, N=40, K=40 pad 64) ----
    float isum;
    {
        f32x4 pacc[3][3];
        #pragma unroll
        for (int aa = 0; aa < 3; ++aa)
            #pragma unroll
            for (int bb = 0; bb < 3; ++bb) pacc[aa][bb] = (f32x4){0.f,0.f,0.f,0.f};
        #pragma unroll
        for (int kk = 0; kk < 2; ++kk){
            bf16x8 afr[3];
            #pragma unroll
            for (int mt = 0; mt < 3; ++mt){
                int row = mt * 16 + frow;      // rows>=36 read adjacent finite LDS; masked below
                if (kk == 0){
                    afr[mt] = *(const bf16x8*)(slice + 3200 + row * 80 + q * 16);
                } else {
                    bf16x8 z = (bf16x8){0,0,0,0,0,0,0,0};
                    if (q == 0) z = *(const bf16x8*)(slice + 3200 + row * 80 + 64); // k=32..39
                    afr[mt] = z;
                }
            }
            #pragma unroll
            for (int nt = 0; nt < 3; ++nt){
                bf16x8 bfr = *(const bf16x8*)(Lb_i2t + (nt * 16 + frow) * 64 + kk * 32 + q * 8);
                #pragma unroll
                for (int mt = 0; mt < 3; ++mt)
                    pacc[mt][nt] = __builtin_amdgcn_mfma_f32_16x16x32_bf16(
                        afr[mt], bfr, pacc[mt][nt], 0, 0, 0);
            }
        }
        float w1 = w1i[bg];
        isum = 0.f;
        #pragma unroll
        for (int mt = 0; mt < 3; ++mt){
            #pragma unroll
            for (int g = 0; g < 4; ++g){
                float sv = pacc[mt][0][g] * pacc[mt][0][g]
                         + pacc[mt][1][g] * pacc[mt][1][g];
                float t2 = pacc[mt][2][g] * pacc[mt][2][g];
                sv += (frow < 8) ? t2 : 0.f;            // n = 32+frow < 40
                sv += __shfl_xor(sv, 1); sv += __shfl_xor(sv, 2);
                sv += __shfl_xor(sv, 4); sv += __shfl_xor(sv, 8);
                int m = mt * 16 + 4 * q + g;
                float nm = __shfl(num2, m);
                float sim = nm / fmaxf(w1 * sqrtf(sv), 1e-8f);
                isum += (m < 36) ? sim : 0.f;           // mask garbage regions
            }
        }
        isum += __shfl_xor(isum, 16);
        isum += __shfl_xor(isum, 32);
    }

    if (lane == 0)
        out[bg * 256 + ig] = tsum * (1.f / 40.f) + isum * (1.f / 36.f) + base;
}

// ---------------------------------------------------------------------------
extern "C" void kernel_launch(void* const* d_in, const int* in_sizes, int n_in,
                              void* d_out, int out_size, void* d_ws, size_t ws_size,
                              hipStream_t stream){
    const float* pool_img = (const float*)d_in[0];
    const float* img_emb  = (const float*)d_in[1];
    const float* pool_txt = (const float*)d_in[2];
    const float* cap_emb  = (const float*)d_in[3];
    float* out = (float*)d_out;

    char* ws = (char*)d_ws;                         // needs ~47 MB
    size_t o = 0;
    u16* imgw = (u16*)(ws + o);  o += (size_t)256 * 37 * 1024 * 2;
    u16* capw = (u16*)(ws + o);  o += (size_t)256 * 41 * 1024 * 2;
    float* G  = (float*)(ws + o); o += (size_t)256 * 36 * 36 * 4;
    float* H  = (float*)(ws + o); o += (size_t)256 * 40 * 40 * 4;
    float* w1i = (float*)(ws + o); o += 1024;
    float* w1t = (float*)(ws + o); o += 1024;
    u16* Lbi = (u16*)(ws + o); o += (size_t)256 * 48 * 64 * 2;   // chol(G)^T, bf16 [48][64]
    u16* Lbc = (u16*)(ws + o); o += (size_t)256 * 48 * 64 * 2;   // chol(H)^T

    pack_kernel<<<19968, 256, 0, stream>>>(pool_img, img_emb, pool_txt, cap_emb, imgw, capw);
    norm_kernel<<<512, 256, 0, stream>>>(pool_img, pool_txt, w1i, w1t);
    gram_kernel<<<512, 256, 0, stream>>>(imgw, capw, G, H);
    chol_kernel<<<128, 256, 0, stream>>>(G, H, Lbi, Lbc);
    fused_kernel<<<16384, 256, 0, stream>>>(imgw, capw, Lbi, Lbc, w1i, w1t, out);
}

// Round 5
// 809.486 us; speedup vs baseline: 1.0463x; 1.0463x over previous
//
#include <hip/hip_runtime.h>

typedef unsigned short u16;
typedef __attribute__((ext_vector_type(8))) short bf16x8;   // 8 bf16 (4 VGPRs)
typedef __attribute__((ext_vector_type(4))) float f32x4;
typedef __attribute__((ext_vector_type(4))) unsigned u32x4;

#define D_EMB 1024
#define NBAT  256
#define AS1 __attribute__((address_space(1)))
#define AS3 __attribute__((address_space(3)))

__device__ __forceinline__ u16 f2bf(float f){
    unsigned int u = __float_as_uint(f);
    unsigned int r = (u + 0x7fffu + ((u >> 16) & 1u)) >> 16;  // RNE
    return (u16)r;
}
__device__ __forceinline__ float leaky(float x){ return x > 0.f ? x : 0.1f * x; }

// truncation-pack two fp32 into 2 bf16 (memory order: a = low u16, b = high u16)
__device__ __forceinline__ unsigned pack2(float a, float b){
    return (__float_as_uint(a) >> 16) | (__float_as_uint(b) & 0xffff0000u);
}

// ---------------------------------------------------------------------------
// Pack img_emb(+pool_img as row 36) and cap_emb(+pool_txt as row 40) to bf16.
// imgw: [256][37][1024] bf16, capw: [256][41][1024] bf16
// ---------------------------------------------------------------------------
__global__ void pack_kernel(const float* __restrict__ pool_img, const float* __restrict__ img_emb,
                            const float* __restrict__ pool_txt, const float* __restrict__ cap_emb,
                            u16* __restrict__ imgw, u16* __restrict__ capw){
    int row = blockIdx.x;            // 0..19967
    const float* src; u16* dst;
    if (row < NBAT * 37){
        int e = row / 37, rr = row - e * 37;
        src = (rr < 36) ? (img_emb + ((size_t)e * 36 + rr) * D_EMB) : (pool_img + (size_t)e * D_EMB);
        dst = imgw + (size_t)row * D_EMB;
    } else {
        int r2 = row - NBAT * 37;
        int e = r2 / 41, rr = r2 - e * 41;
        src = (rr < 40) ? (cap_emb + ((size_t)e * 40 + rr) * D_EMB) : (pool_txt + (size_t)e * D_EMB);
        dst = capw + (size_t)r2 * D_EMB;
    }
    int t = threadIdx.x;             // 256 threads, 4 floats each
    float4 v = ((const float4*)src)[t];
    unsigned long long pk = (unsigned long long)f2bf(v.x)
        | ((unsigned long long)f2bf(v.y) << 16)
        | ((unsigned long long)f2bf(v.z) << 32)
        | ((unsigned long long)f2bf(v.w) << 48);
    *(unsigned long long*)(dst + (size_t)t * 4) = pk;
}

// ---------------------------------------------------------------------------
// Pool-vector norms
// ---------------------------------------------------------------------------
__global__ void norm_kernel(const float* __restrict__ pool_img, const float* __restrict__ pool_txt,
                            float* __restrict__ w1i, float* __restrict__ w1t){
    __shared__ float red[256];
    int v = blockIdx.x;              // 0..511
    const float* src = (v < 256) ? (pool_img + (size_t)v * D_EMB)
                                 : (pool_txt + (size_t)(v - 256) * D_EMB);
    int t = threadIdx.x;
    float4 x = ((const float4*)src)[t];
    red[t] = x.x*x.x + x.y*x.y + x.z*x.z + x.w*x.w;
    __syncthreads();
    for (int off = 128; off > 0; off >>= 1){
        if (t < off) red[t] += red[t + off];
        __syncthreads();
    }
    if (t == 0){
        float n = sqrtf(red[0]);
        if (v < 256) w1i[v] = n; else w1t[v - 256] = n;
    }
}

// ---------------------------------------------------------------------------
// MFMA Gram kernel (reads packed bf16): blk<256 -> G[b]=E_img E_img^T (R=36),
// else H[b]=E_cap E_cap^T (R=40). Frag-order staging via global_load_lds.
// ---------------------------------------------------------------------------
__launch_bounds__(256, 2)
__global__ void gram_kernel(const u16* __restrict__ imgw, const u16* __restrict__ capw,
                            float* __restrict__ G, float* __restrict__ H){
    __shared__ __align__(16) char gsm[6144];    // 3 tiles x 2 kk x 64 lanes x 16B
    int blk = blockIdx.x;
    int tid = threadIdx.x, lane = tid & 63;
    int wave = __builtin_amdgcn_readfirstlane(tid >> 6);
    int frow = lane & 15, q = lane >> 4;

    const u16* E; float* Gout; int R;
    if (blk < NBAT){ E = imgw + (size_t)blk * 37 * D_EMB; Gout = G + (size_t)blk * 1296; R = 36; }
    else { int b = blk - NBAT; E = capw + (size_t)b * 41 * D_EMB; Gout = H + (size_t)b * 1600; R = 40; }

    {   // zero staging once (pad rows stay zero)
        uint4 z = {0u,0u,0u,0u};
        for (int off = tid * 16; off < 6144; off += 4096) *(uint4*)(gsm + off) = z;
    }

    // staging groups g = kk*3 + t, g in [0,6)
    const u16* gsrc[2]; int goff[2]; bool gval[2];
    #pragma unroll
    for (int j = 0; j < 2; ++j){
        int g = wave + j * 4;
        gval[j] = false; gsrc[j] = E; goff[j] = 0;
        if (g < 6){
            int kk = g / 3, t = g - kk * 3;
            int row = t * 16 + frow;
            gsrc[j] = E + (size_t)row * D_EMB + kk * 32 + q * 8;
            goff[j] = g * 1024;
            gval[j] = (row < R);
        }
    }

    int wm = wave >> 1, wn = wave & 1;
    int nTm = wm ? 1 : 2, nTn = wn ? 1 : 2;
    f32x4 acc[2][2];
    #pragma unroll
    for (int a = 0; a < 2; ++a)
        #pragma unroll
        for (int b = 0; b < 2; ++b) acc[a][b] = (f32x4){0.f,0.f,0.f,0.f};

    for (int c = 0; c < 16; ++c){
        __syncthreads();
        #pragma unroll
        for (int j = 0; j < 2; ++j){
            if (gval[j]){
                __builtin_amdgcn_global_load_lds(
                    (const AS1 void*)(const void*)(gsrc[j] + c * 64),
                    (AS3 void*)(void*)(gsm + goff[j] + lane * 16),
                    16, 0, 0);
            }
        }
        __syncthreads();
        #pragma unroll
        for (int kk = 0; kk < 2; ++kk){
            bf16x8 fA[2], fB[2];
            #pragma unroll
            for (int mi = 0; mi < 2; ++mi)
                if (mi < nTm) fA[mi] = *(const bf16x8*)(gsm + ((kk * 3 + (wm + mi * 2)) * 64 + lane) * 16);
            #pragma unroll
            for (int ni = 0; ni < 2; ++ni)
                if (ni < nTn) fB[ni] = *(const bf16x8*)(gsm + ((kk * 3 + (wn + ni * 2)) * 64 + lane) * 16);
            #pragma unroll
            for (int mi = 0; mi < 2; ++mi)
                if (mi < nTm)
                    #pragma unroll
                    for (int ni = 0; ni < 2; ++ni)
                        if (ni < nTn)
                            acc[mi][ni] = __builtin_amdgcn_mfma_f32_16x16x32_bf16(
                                fA[mi], fB[ni], acc[mi][ni], 0, 0, 0);
        }
    }

    #pragma unroll
    for (int mi = 0; mi < 2; ++mi){
        if (mi < nTm){
            int tm = wm + mi * 2;
            #pragma unroll
            for (int ni = 0; ni < 2; ++ni){
                if (ni < nTn){
                    int tn = wn + ni * 2;
                    int col = tn * 16 + frow;
                    if (col < R){
                        #pragma unroll
                        for (int g = 0; g < 4; ++g){
                            int row = tm * 16 + q * 4 + g;
                            if (row < R) Gout[row * R + col] = acc[mi][ni][g];
                        }
                    }
                }
            }
        }
    }
}

// ---------------------------------------------------------------------------
// Cholesky kernel: per matrix, G = L·L^T (fp32), store L^T rows as bf16 in
// [48][64] zero-padded layout: Lb[n][k] = L[k][n]. One wave per matrix.
// ---------------------------------------------------------------------------
template<int R>
__device__ __forceinline__ void chol_wave(const float* __restrict__ src,
                                          u16* __restrict__ dst, int lane){
    int r = lane;
    bool act = (r < R);
    const float* row = src + (size_t)(act ? r : 0) * R;
    float a[R];
    #pragma unroll
    for (int k = 0; k < R; ++k) a[k] = act ? row[k] : 0.f;
    #pragma unroll
    for (int j = 0; j < R; ++j){
        float ajj = __shfl(a[j], j);
        float inv = (ajj > 1e-12f) ? rsqrtf(ajj) : 0.f;
        float lrj = a[j] * inv;
        if (r < j || !act) lrj = 0.f;           // strict lower + diag only
        dst[j * 64 + lane] = f2bf(lrj);         // row j of Lb = column j of L
        #pragma unroll
        for (int k = j + 1; k < R; ++k){
            float lkj = __shfl(lrj, k);
            a[k] = fmaf(-lrj, lkj, a[k]);
        }
    }
    #pragma unroll
    for (int j = R; j < 48; ++j) dst[j * 64 + lane] = 0;   // zero pad rows
}

__global__ void chol_kernel(const float* __restrict__ G, const float* __restrict__ H,
                            u16* __restrict__ Lbi, u16* __restrict__ Lbc){
    int lane = threadIdx.x & 63;
    int wave = threadIdx.x >> 6;
    int id = blockIdx.x * 4 + wave;   // 0..511 (uniform branch per block)
    if (id < NBAT) chol_wave<36>(G + (size_t)id * 1296, Lbi + (size_t)id * 3072, lane);
    else           chol_wave<40>(H + (size_t)(id - NBAT) * 1600, Lbc + (size_t)(id - NBAT) * 3072, lane);
}

// ---------------------------------------------------------------------------
// Fused main kernel. One block = 2 images x 2 captions.
// GEMM phase: double-buffered K=32 chunks, prefetch-then-compute, 1 barrier
// per chunk.
// Post phase (R5 rework): NOTHING is materialized in registers or staged.
//  - A-fragments (softmax weights) computed ON THE FLY from Sv in frag order:
//    each lane builds exactly its 8 bf16 elements (exp in frag layout), so
//    u/v never exist as arrays -> no spill (R2:525MB, R3:132MB, R4:262MB).
//  - num dot-products come FREE from the MFMA's padded N-dim: p / qv are
//    injected as B-row n=36 (t2i) / n=40 (i2t); num[m] = Y[m][36|40] read
//    from pacc[.][2] at frow==4|8.
//  - Call is never overwritten -> no overlay barrier; rnb/cnb are wave-
//    private slices -> no barrier either.
// All potentially-OOB LDS indices are clamped; garbage rows/cols masked by
// select (never multiplied), so no NaN/Inf leakage.
// ---------------------------------------------------------------------------
__launch_bounds__(256, 5)
__global__ void fused_kernel(const u16* __restrict__ imgw, const u16* __restrict__ capw,
                             const u16* __restrict__ Lbi, const u16* __restrict__ Lbc,
                             const float* __restrict__ w1i, const float* __restrict__ w1t,
                             float* __restrict__ out){
    __shared__ __align__(16) char smem[26624];
    float* Call = (float*)smem;                 // overlay after GEMM: [74][85]
    float* rnb  = (float*)(smem + 25160);       // [4][36]
    float* cnb  = (float*)(smem + 25736);       // [4][40]

    int tid  = threadIdx.x;
    int lane = tid & 63;
    int wave = __builtin_amdgcn_readfirstlane(tid >> 6);
    int frow = lane & 15, q = lane >> 4;

    int lin = blockIdx.x;
    int xcd = lin & 7;                   // XCD-aware swizzle (16384 % 8 == 0, bijective)
    int s   = lin >> 3;                  // 0..2047
    int b_t = (xcd << 4) | (s & 15);     // each XCD owns 16 b-tiles
    int i_t = s >> 4;                    // 0..127
    int b0 = b_t * 2, i0 = i_t * 2;
    const u16* Ag = imgw + (size_t)b0 * 37 * D_EMB;   // 74 rows
    const u16* Bg = capw + (size_t)i0 * 41 * D_EMB;   // 82 rows

    {   // zero staging region once (pad slots stay zero forever)
        uint4 z = {0u,0u,0u,0u};
        for (int off = tid * 16; off < 22528; off += 4096) *(uint4*)(smem + off) = z;
    }

    // staging groups per K=32 chunk: 11 groups (A tiles 0..4, B tiles 5..10);
    // wave w handles g in {w, w+4, w+8}. Per-chunk buffer: A at g*1024,
    // B at 5120 + gb*1024; buffer base alternates 0 / 11264.
    const u16* gsrc[3]; int goff[3]; bool gval[3];
    #pragma unroll
    for (int j = 0; j < 3; ++j){
        int g = wave + j * 4;
        gval[j] = false; gsrc[j] = Ag; goff[j] = 0;
        if (g < 11){
            if (g < 5){
                int row = g * 16 + frow;
                gsrc[j] = Ag + (size_t)row * D_EMB + q * 8;
                goff[j] = g * 1024;
                gval[j] = (row < 74);
            } else {
                int gb = g - 5;
                int row = gb * 16 + frow;
                gsrc[j] = Bg + (size_t)row * D_EMB + q * 8;
                goff[j] = 5120 + gb * 1024;
                gval[j] = (row < 82);
            }
        }
    }

    int wm = wave >> 1, wn = wave & 1;     // 2x2 wave grid over 5x6 MFMA tiles
    int nTm = wm ? 2 : 3;                  // m-tiles {wm, wm+2, wm+4} < 5
    f32x4 acc[3][3];
    #pragma unroll
    for (int aa = 0; aa < 3; ++aa)
        #pragma unroll
        for (int bb = 0; bb < 3; ++bb) acc[aa][bb] = (f32x4){0.f, 0.f, 0.f, 0.f};

    __syncthreads();                       // zero-init visible before staging

    // prologue: stage chunk 0 into buffer 0
    #pragma unroll
    for (int j = 0; j < 3; ++j){
        if (gval[j]){
            __builtin_amdgcn_global_load_lds(
                (const AS1 void*)(const void*)(gsrc[j]),
                (AS3 void*)(void*)(smem + goff[j] + lane * 16),
                16, 0, 0);
        }
    }
    __syncthreads();                       // chunk 0 landed

    for (int c = 0; c < 32; ++c){          // K chunks of 32
        if (c < 31){                       // issue NEXT chunk first (prefetch)
            int nb = ((c + 1) & 1) * 11264;
            #pragma unroll
            for (int j = 0; j < 3; ++j){
                if (gval[j]){
                    __builtin_amdgcn_global_load_lds(
                        (const AS1 void*)(const void*)(gsrc[j] + (c + 1) * 32),
                        (AS3 void*)(void*)(smem + nb + goff[j] + lane * 16),
                        16, 0, 0);
                }
            }
        }
        int cb = (c & 1) * 11264;          // compute CURRENT chunk under the loads
        bf16x8 bfr[3];
        #pragma unroll
        for (int ni = 0; ni < 3; ++ni){
            int tn = wn + ni * 2;
            bfr[ni] = *(const bf16x8*)(smem + cb + 5120 + tn * 1024 + lane * 16);
        }
        #pragma unroll
        for (int mi = 0; mi < 3; ++mi){
            if (mi < nTm){
                int tm = wm + mi * 2;
                bf16x8 af = *(const bf16x8*)(smem + cb + tm * 1024 + lane * 16);
                #pragma unroll
                for (int ni = 0; ni < 3; ++ni){
                    acc[mi][ni] = __builtin_amdgcn_mfma_f32_16x16x32_bf16(
                        af, bfr[ni], acc[mi][ni], 0, 0, 0);
                }
            }
        }
        __syncthreads();                   // drains prefetch (overlapped) + guards buffer swap
    }

    // C/D layout: col = lane&15 (B-row), row = (lane>>4)*4 + reg (A-row)
    #pragma unroll
    for (int mi = 0; mi < 3; ++mi){
        if (mi < nTm){
            int tm = wm + mi * 2;
            #pragma unroll
            for (int ni = 0; ni < 3; ++ni){
                int tn = wn + ni * 2;
                int col = tn * 16 + frow;
                int rbase = tm * 16 + q * 4;
                if (col < 82){
                    #pragma unroll
                    for (int g = 0; g < 4; ++g){
                        int rowc = rbase + g;
                        if (rowc < 74) Call[rowc * 85 + col] = acc[mi][ni][g];
                    }
                }
            }
        }
    }
    __syncthreads();                       // C complete; post phase is read-only on Call

    // ----- post-processing: one wave per (b,i) pair -----
    int pb = wave >> 1, pi = wave & 1;
    int bg = b0 + pb, ig = i0 + pi;
    const float* Sv = Call + (pb * 37) * 85 + pi * 41;  // S[r*85+l]; p[r]=S[r*85+40]; qv[l]=S[36*85+l]
    const u16* Lb_t2i = Lbi + (size_t)bg * 3072;        // [48][64] bf16, B[n][k]=L[k][n]
    const u16* Lb_i2t = Lbc + (size_t)ig * 3072;

    {   // row norms over words (lanes = regions); wave-private slice, no barrier
        int r0 = (lane < 36) ? lane : 35;
        float s2 = 0.f;
        #pragma unroll
        for (int l = 0; l < 40; ++l){ float x = leaky(Sv[r0 * 85 + l]); s2 = fmaf(x, x, s2); }
        if (lane < 36) rnb[wave * 36 + lane] = 1.f / (sqrtf(s2) + 1e-8f);
    }
    {   // column norms over regions (lanes = words)
        int l0 = (lane < 40) ? lane : 39;
        float s2 = 0.f;
        #pragma unroll
        for (int r = 0; r < 36; ++r){ float x = leaky(Sv[r * 85 + l0]); s2 = fmaf(x, x, s2); }
        if (lane < 40) cnb[wave * 40 + lane] = 1.f / (sqrtf(s2) + 1e-8f);
    }
    float base = Sv[36 * 85 + 40];

    // ---- t2i:  Y = U·L_img (M=40 words, K=36 regions pad 64, N=36 + num row)
    //      U[m][k] = exp(9*leaky(S[k][m])*rnb[k]) built per-fragment on the fly;
    //      B-row n=36 carries p[k] -> Y[m][36] = num[m].
    float tsum;
    {
        f32x4 pacc[3][3];
        #pragma unroll
        for (int aa = 0; aa < 3; ++aa)
            #pragma unroll
            for (int bb = 0; bb < 3; ++bb) pacc[aa][bb] = (f32x4){0.f,0.f,0.f,0.f};
        #pragma unroll
        for (int kk = 0; kk < 2; ++kk){
            float rn[8];
            #pragma unroll
            for (int j = 0; j < 8; ++j){
                int k = kk * 32 + q * 8 + j;
                int kc = (k < 36) ? k : 35;                  // clamp: in-bounds reads
                rn[j] = (k < 36) ? rnb[wave * 36 + kc] : 0.f;
            }
            u32x4 pw;                                        // p-injection (B row 36)
            #pragma unroll
            for (int jj = 0; jj < 4; ++jj){
                int k0 = kk * 32 + q * 8 + jj * 2, k1 = k0 + 1;
                int c0 = (k0 < 36) ? k0 : 35, c1 = (k1 < 36) ? k1 : 35;
                float p0 = (k0 < 36) ? Sv[c0 * 85 + 40] : 0.f;
                float p1 = (k1 < 36) ? Sv[c1 * 85 + 40] : 0.f;
                pw[jj] = pack2(p0, p1);
            }
            bf16x8 afr[3];
            #pragma unroll
            for (int mt = 0; mt < 3; ++mt){
                int m = mt * 16 + frow;      // word col; m>=40 garbage, masked at reduce
                u32x4 aw;
                #pragma unroll
                for (int jj = 0; jj < 4; ++jj){
                    int k0 = kk * 32 + q * 8 + jj * 2, k1 = k0 + 1;
                    int c0 = (k0 < 36) ? k0 : 35, c1 = (k1 < 36) ? k1 : 35;
                    float e0 = __expf(9.f * leaky(Sv[c0 * 85 + m]) * rn[jj * 2]);
                    float e1 = __expf(9.f * leaky(Sv[c1 * 85 + m]) * rn[jj * 2 + 1]);
                    e0 = (k0 < 36) ? e0 : 0.f;
                    e1 = (k1 < 36) ? e1 : 0.f;
                    aw[jj] = pack2(e0, e1);
                }
                afr[mt] = __builtin_bit_cast(bf16x8, aw);
            }
            #pragma unroll
            for (int nt = 0; nt < 3; ++nt){
                bf16x8 bfr = *(const bf16x8*)(Lb_t2i + (nt * 16 + frow) * 64 + kk * 32 + q * 8);
                if (nt == 2 && frow == 4) bfr = __builtin_bit_cast(bf16x8, pw);
                #pragma unroll
                for (int mt = 0; mt < 3; ++mt)
                    pacc[mt][nt] = __builtin_amdgcn_mfma_f32_16x16x32_bf16(
                        afr[mt], bfr, pacc[mt][nt], 0, 0, 0);
            }
        }
        // zz[m] = sum_{n<36} Y[m][n]^2 ; num[m] = Y[m][36] (frow==4, nt=2)
        float w1 = w1t[ig];
        tsum = 0.f;
        #pragma unroll
        for (int mt = 0; mt < 3; ++mt){
            #pragma unroll
            for (int g = 0; g < 4; ++g){
                float sv = pacc[mt][0][g] * pacc[mt][0][g]
                         + pacc[mt][1][g] * pacc[mt][1][g];
                float t2 = pacc[mt][2][g] * pacc[mt][2][g];
                sv += (frow < 4) ? t2 : 0.f;            // n = 32+frow < 36
                sv += __shfl_xor(sv, 1); sv += __shfl_xor(sv, 2);
                sv += __shfl_xor(sv, 4); sv += __shfl_xor(sv, 8);
                float nm = __shfl(pacc[mt][2][g], (lane & 48) + 4);
                int m = mt * 16 + 4 * q + g;
                float sim = nm / fmaxf(w1 * sqrtf(sv), 1e-8f);
                tsum += (m < 40) ? sim : 0.f;           // mask garbage words
            }
        }
        tsum += __shfl_xor(tsum, 16);
        tsum += __shfl_xor(tsum, 32);
    }

    // ---- i2t:  Y = V·L_cap (M=36 regions, K=40 words pad 64, N=40 + num row)
    //      V[m][k] = exp(9*leaky(S[m][k])*cnb[k]); B-row n=40 carries qv[k].
    float isum;
    {
        f32x4 pacc[3][3];
        #pragma unroll
        for (int aa = 0; aa < 3; ++aa)
            #pragma unroll
            for (int bb = 0; bb < 3; ++bb) pacc[aa][bb] = (f32x4){0.f,0.f,0.f,0.f};
        #pragma unroll
        for (int kk = 0; kk < 2; ++kk){
            float cn[8];
            #pragma unroll
            for (int j = 0; j < 8; ++j){
                int k = kk * 32 + q * 8 + j;
                int kc = (k < 40) ? k : 39;
                cn[j] = (k < 40) ? cnb[wave * 40 + kc] : 0.f;
            }
            u32x4 qw;                                        // qv-injection (B row 40)
            #pragma unroll
            for (int jj = 0; jj < 4; ++jj){
                int k0 = kk * 32 + q * 8 + jj * 2, k1 = k0 + 1;
                int c0 = (k0 < 40) ? k0 : 39, c1 = (k1 < 40) ? k1 : 39;
                float q0 = (k0 < 40) ? Sv[36 * 85 + c0] : 0.f;
                float q1 = (k1 < 40) ? Sv[36 * 85 + c1] : 0.f;
                qw[jj] = pack2(q0, q1);
            }
            bf16x8 afr[3];
            #pragma unroll
            for (int mt = 0; mt < 3; ++mt){
                int m = mt * 16 + frow;      // region row; m>=36 garbage, masked at reduce
                int mr = (m < 36) ? m : 35;                  // clamp: in-bounds reads
                u32x4 aw;
                #pragma unroll
                for (int jj = 0; jj < 4; ++jj){
                    int k0 = kk * 32 + q * 8 + jj * 2, k1 = k0 + 1;
                    int c0 = (k0 < 40) ? k0 : 39, c1 = (k1 < 40) ? k1 : 39;
                    float e0 = __expf(9.f * leaky(Sv[mr * 85 + c0]) * cn[jj * 2]);
                    float e1 = __expf(9.f * leaky(Sv[mr * 85 + c1]) * cn[jj * 2 + 1]);
                    e0 = (k0 < 40) ? e0 : 0.f;
                    e1 = (k1 < 40) ? e1 : 0.f;
                    aw[jj] = pack2(e0, e1);
                }
                afr[mt] = __builtin_bit_cast(bf16x8, aw);
            }
            #pragma unroll
            for (int nt = 0; nt < 3; ++nt){
                bf16x8 bfr = *(const bf16x8*)(Lb_i2t + (nt * 16 + frow) * 64 + kk * 32 + q * 8);
                if (nt == 2 && frow == 8) bfr = __builtin_bit_cast(bf16x8, qw);
                #pragma unroll
                for (int mt = 0; mt < 3; ++mt)
                    pacc[mt][nt] = __builtin_amdgcn_mfma_f32_16x16x32_bf16(
                        afr[mt], bfr, pacc[mt][nt], 0, 0, 0);
            }
        }
        float w1 = w1i[bg];
        isum = 0.f;
        #pragma unroll
        for (int mt = 0; mt < 3; ++mt){
            #pragma unroll
            for (int g = 0; g < 4; ++g){
                float sv = pacc[mt][0][g] * pacc[mt][0][g]
                         + pacc[mt][1][g] * pacc[mt][1][g];
                float t2 = pacc[mt][2][g] * pacc[mt][2][g];
                sv += (frow < 8) ? t2 : 0.f;            // n = 32+frow < 40
                sv += __shfl_xor(sv, 1); sv += __shfl_xor(sv, 2);
                sv += __shfl_xor(sv, 4); sv += __shfl_xor(sv, 8);
                float nm = __shfl(pacc[mt][2][g], (lane & 48) + 8);
                int m = mt * 16 + 4 * q + g;
                float sim = nm / fmaxf(w1 * sqrtf(sv), 1e-8f);
                isum += (m < 36) ? sim : 0.f;           // mask garbage regions
            }
        }
        isum += __shfl_xor(isum, 16);
        isum += __shfl_xor(isum, 32);
    }

    if (lane == 0)
        out[bg * 256 + ig] = tsum * (1.f / 40.f) + isum * (1.f / 36.f) + base;
}

// ---------------------------------------------------------------------------
extern "C" void kernel_launch(void* const* d_in, const int* in_sizes, int n_in,
                              void* d_out, int out_size, void* d_ws, size_t ws_size,
                              hipStream_t stream){
    const float* pool_img = (const float*)d_in[0];
    const float* img_emb  = (const float*)d_in[1];
    const float* pool_txt = (const float*)d_in[2];
    const float* cap_emb  = (const float*)d_in[3];
    float* out = (float*)d_out;

    char* ws = (char*)d_ws;                         // needs ~47 MB
    size_t o = 0;
    u16* imgw = (u16*)(ws + o);  o += (size_t)256 * 37 * 1024 * 2;
    u16* capw = (u16*)(ws + o);  o += (size_t)256 * 41 * 1024 * 2;
    float* G  = (float*)(ws + o); o += (size_t)256 * 36 * 36 * 4;
    float* H  = (float*)(ws + o); o += (size_t)256 * 40 * 40 * 4;
    float* w1i = (float*)(ws + o); o += 1024;
    float* w1t = (float*)(ws + o); o += 1024;
    u16* Lbi = (u16*)(ws + o); o += (size_t)256 * 48 * 64 * 2;   // chol(G)^T, bf16 [48][64]
    u16* Lbc = (u16*)(ws + o); o += (size_t)256 * 48 * 64 * 2;   // chol(H)^T

    pack_kernel<<<19968, 256, 0, stream>>>(pool_img, img_emb, pool_txt, cap_emb, imgw, capw);
    norm_kernel<<<512, 256, 0, stream>>>(pool_img, pool_txt, w1i, w1t);
    gram_kernel<<<512, 256, 0, stream>>>(imgw, capw, G, H);
    chol_kernel<<<128, 256, 0, stream>>>(G, H, Lbi, Lbc);
    fused_kernel<<<16384, 256, 0, stream>>>(imgw, capw, Lbi, Lbc, w1i, w1t, out);
}

// Round 6
// 806.802 us; speedup vs baseline: 1.0498x; 1.0033x over previous
//
#include <hip/hip_runtime.h>

typedef unsigned short u16;
typedef __attribute__((ext_vector_type(8))) short bf16x8;   // 8 bf16 (4 VGPRs)
typedef __attribute__((ext_vector_type(4))) float f32x4;
typedef __attribute__((ext_vector_type(4))) unsigned u32x4;

#define D_EMB 1024
#define NBAT  256
#define AS1 __attribute__((address_space(1)))
#define AS3 __attribute__((address_space(3)))

__device__ __forceinline__ u16 f2bf(float f){
    unsigned int u = __float_as_uint(f);
    unsigned int r = (u + 0x7fffu + ((u >> 16) & 1u)) >> 16;  // RNE
    return (u16)r;
}
__device__ __forceinline__ float leaky(float x){ return x > 0.f ? x : 0.1f * x; }

// truncation-pack two fp32 into 2 bf16 (memory order: a = low u16, b = high u16)
__device__ __forceinline__ unsigned pack2(float a, float b){
    return (__float_as_uint(a) >> 16) | (__float_as_uint(b) & 0xffff0000u);
}

// ---------------------------------------------------------------------------
// Pack img_emb(+pool_img as row 36) and cap_emb(+pool_txt as row 40) to bf16,
// and (for pool rows) also emit the pool-vector L2 norm (norm_kernel folded).
// imgw: [256][37][1024] bf16, capw: [256][41][1024] bf16
// ---------------------------------------------------------------------------
__global__ void pack_kernel(const float* __restrict__ pool_img, const float* __restrict__ img_emb,
                            const float* __restrict__ pool_txt, const float* __restrict__ cap_emb,
                            u16* __restrict__ imgw, u16* __restrict__ capw,
                            float* __restrict__ w1i, float* __restrict__ w1t){
    __shared__ float red[256];
    int row = blockIdx.x;            // 0..19967
    const float* src; u16* dst;
    bool is_pool; float* wout;
    if (row < NBAT * 37){
        int e = row / 37, rr = row - e * 37;
        is_pool = (rr == 36);
        src = (rr < 36) ? (img_emb + ((size_t)e * 36 + rr) * D_EMB) : (pool_img + (size_t)e * D_EMB);
        dst = imgw + (size_t)row * D_EMB;
        wout = w1i + e;
    } else {
        int r2 = row - NBAT * 37;
        int e = r2 / 41, rr = r2 - e * 41;
        is_pool = (rr == 40);
        src = (rr < 40) ? (cap_emb + ((size_t)e * 40 + rr) * D_EMB) : (pool_txt + (size_t)e * D_EMB);
        dst = capw + (size_t)r2 * D_EMB;
        wout = w1t + e;
    }
    int t = threadIdx.x;             // 256 threads, 4 floats each
    float4 v = ((const float4*)src)[t];
    unsigned long long pk = (unsigned long long)f2bf(v.x)
        | ((unsigned long long)f2bf(v.y) << 16)
        | ((unsigned long long)f2bf(v.z) << 32)
        | ((unsigned long long)f2bf(v.w) << 48);
    *(unsigned long long*)(dst + (size_t)t * 4) = pk;
    if (is_pool){                    // block-uniform branch
        red[t] = v.x*v.x + v.y*v.y + v.z*v.z + v.w*v.w;
        __syncthreads();
        for (int off = 128; off > 0; off >>= 1){
            if (t < off) red[t] += red[t + off];
            __syncthreads();
        }
        if (t == 0) *wout = sqrtf(red[0]);
    }
}

// ---------------------------------------------------------------------------
// MFMA Gram kernel (reads packed bf16): blk<256 -> G[b]=E_img E_img^T (R=36),
// else H[b]=E_cap E_cap^T (R=40). Frag-order staging via global_load_lds.
// ---------------------------------------------------------------------------
__launch_bounds__(256, 2)
__global__ void gram_kernel(const u16* __restrict__ imgw, const u16* __restrict__ capw,
                            float* __restrict__ G, float* __restrict__ H){
    __shared__ __align__(16) char gsm[6144];    // 3 tiles x 2 kk x 64 lanes x 16B
    int blk = blockIdx.x;
    int tid = threadIdx.x, lane = tid & 63;
    int wave = __builtin_amdgcn_readfirstlane(tid >> 6);
    int frow = lane & 15, q = lane >> 4;

    const u16* E; float* Gout; int R;
    if (blk < NBAT){ E = imgw + (size_t)blk * 37 * D_EMB; Gout = G + (size_t)blk * 1296; R = 36; }
    else { int b = blk - NBAT; E = capw + (size_t)b * 41 * D_EMB; Gout = H + (size_t)b * 1600; R = 40; }

    {   // zero staging once (pad rows stay zero)
        uint4 z = {0u,0u,0u,0u};
        for (int off = tid * 16; off < 6144; off += 4096) *(uint4*)(gsm + off) = z;
    }

    // staging groups g = kk*3 + t, g in [0,6)
    const u16* gsrc[2]; int goff[2]; bool gval[2];
    #pragma unroll
    for (int j = 0; j < 2; ++j){
        int g = wave + j * 4;
        gval[j] = false; gsrc[j] = E; goff[j] = 0;
        if (g < 6){
            int kk = g / 3, t = g - kk * 3;
            int row = t * 16 + frow;
            gsrc[j] = E + (size_t)row * D_EMB + kk * 32 + q * 8;
            goff[j] = g * 1024;
            gval[j] = (row < R);
        }
    }

    int wm = wave >> 1, wn = wave & 1;
    int nTm = wm ? 1 : 2, nTn = wn ? 1 : 2;
    f32x4 acc[2][2];
    #pragma unroll
    for (int a = 0; a < 2; ++a)
        #pragma unroll
        for (int b = 0; b < 2; ++b) acc[a][b] = (f32x4){0.f,0.f,0.f,0.f};

    for (int c = 0; c < 16; ++c){
        __syncthreads();
        #pragma unroll
        for (int j = 0; j < 2; ++j){
            if (gval[j]){
                __builtin_amdgcn_global_load_lds(
                    (const AS1 void*)(const void*)(gsrc[j] + c * 64),
                    (AS3 void*)(void*)(gsm + goff[j] + lane * 16),
                    16, 0, 0);
            }
        }
        __syncthreads();
        #pragma unroll
        for (int kk = 0; kk < 2; ++kk){
            bf16x8 fA[2], fB[2];
            #pragma unroll
            for (int mi = 0; mi < 2; ++mi)
                if (mi < nTm) fA[mi] = *(const bf16x8*)(gsm + ((kk * 3 + (wm + mi * 2)) * 64 + lane) * 16);
            #pragma unroll
            for (int ni = 0; ni < 2; ++ni)
                if (ni < nTn) fB[ni] = *(const bf16x8*)(gsm + ((kk * 3 + (wn + ni * 2)) * 64 + lane) * 16);
            #pragma unroll
            for (int mi = 0; mi < 2; ++mi)
                if (mi < nTm)
                    #pragma unroll
                    for (int ni = 0; ni < 2; ++ni)
                        if (ni < nTn)
                            acc[mi][ni] = __builtin_amdgcn_mfma_f32_16x16x32_bf16(
                                fA[mi], fB[ni], acc[mi][ni], 0, 0, 0);
        }
    }

    #pragma unroll
    for (int mi = 0; mi < 2; ++mi){
        if (mi < nTm){
            int tm = wm + mi * 2;
            #pragma unroll
            for (int ni = 0; ni < 2; ++ni){
                if (ni < nTn){
                    int tn = wn + ni * 2;
                    int col = tn * 16 + frow;
                    if (col < R){
                        #pragma unroll
                        for (int g = 0; g < 4; ++g){
                            int row = tm * 16 + q * 4 + g;
                            if (row < R) Gout[row * R + col] = acc[mi][ni][g];
                        }
                    }
                }
            }
        }
    }
}

// ---------------------------------------------------------------------------
// Cholesky kernel: per matrix, G = L·L^T (fp32), store L^T rows as bf16 in
// [48][64] zero-padded layout: Lb[n][k] = L[k][n]. One wave per matrix.
// ---------------------------------------------------------------------------
template<int R>
__device__ __forceinline__ void chol_wave(const float* __restrict__ src,
                                          u16* __restrict__ dst, int lane){
    int r = lane;
    bool act = (r < R);
    const float* row = src + (size_t)(act ? r : 0) * R;
    float a[R];
    #pragma unroll
    for (int k = 0; k < R; ++k) a[k] = act ? row[k] : 0.f;
    #pragma unroll
    for (int j = 0; j < R; ++j){
        float ajj = __shfl(a[j], j);
        float inv = (ajj > 1e-12f) ? rsqrtf(ajj) : 0.f;
        float lrj = a[j] * inv;
        if (r < j || !act) lrj = 0.f;           // strict lower + diag only
        dst[j * 64 + lane] = f2bf(lrj);         // row j of Lb = column j of L
        #pragma unroll
        for (int k = j + 1; k < R; ++k){
            float lkj = __shfl(lrj, k);
            a[k] = fmaf(-lrj, lkj, a[k]);
        }
    }
    #pragma unroll
    for (int j = R; j < 48; ++j) dst[j * 64 + lane] = 0;   // zero pad rows
}

__global__ void chol_kernel(const float* __restrict__ G, const float* __restrict__ H,
                            u16* __restrict__ Lbi, u16* __restrict__ Lbc){
    int lane = threadIdx.x & 63;
    int wave = threadIdx.x >> 6;
    int id = blockIdx.x * 4 + wave;   // 0..511 (uniform branch per block)
    if (id < NBAT) chol_wave<36>(G + (size_t)id * 1296, Lbi + (size_t)id * 3072, lane);
    else           chol_wave<40>(H + (size_t)(id - NBAT) * 1600, Lbc + (size_t)(id - NBAT) * 3072, lane);
}

// ---------------------------------------------------------------------------
// Fused main kernel. One block = 2 images x 2 captions.
// GEMM phase: REVERTED to the R0 structure (best end-to-end evidence: 712us)
// -- 16 chunks of K=64, 22 staging groups (6/wave), loads issued between two
// barriers, compute in a separate phase. The R2-R5 K=32 prefetch pipeline
// interleaved gload_lds LDS-writes with the ds_read/MFMA critical path and
// doubled loop bookkeeping; with 5 blocks/CU the TLP already hides load
// latency, so the pipeline only added cost (768 vs 712 with post held const).
// Post phase: R5's spill-free on-the-fly MFMA form (weights built per
// fragment from Sv, num via padded-N injection). rnb/cnb carry the 9x fold.
// ---------------------------------------------------------------------------
__launch_bounds__(256, 5)
__global__ void fused_kernel(const u16* __restrict__ imgw, const u16* __restrict__ capw,
                             const u16* __restrict__ Lbi, const u16* __restrict__ Lbc,
                             const float* __restrict__ w1i, const float* __restrict__ w1t,
                             float* __restrict__ out){
    __shared__ __align__(16) char smem[26624];
    float* Call = (float*)smem;                 // overlay after GEMM: [74][85]
    float* rnb  = (float*)(smem + 25160);       // [4][36]
    float* cnb  = (float*)(smem + 25736);       // [4][40]

    int tid  = threadIdx.x;
    int lane = tid & 63;
    int wave = __builtin_amdgcn_readfirstlane(tid >> 6);
    int frow = lane & 15, q = lane >> 4;

    int lin = blockIdx.x;
    int xcd = lin & 7;                   // XCD-aware swizzle (16384 % 8 == 0, bijective)
    int s   = lin >> 3;                  // 0..2047
    int b_t = (xcd << 4) | (s & 15);     // each XCD owns 16 b-tiles
    int i_t = s >> 4;                    // 0..127
    int b0 = b_t * 2, i0 = i_t * 2;
    const u16* Ag = imgw + (size_t)b0 * 37 * D_EMB;   // 74 rows
    const u16* Bg = capw + (size_t)i0 * 41 * D_EMB;   // 82 rows

    {   // zero staging region once (pad slots stay zero forever)
        uint4 z = {0u,0u,0u,0u};
        for (int off = tid * 16; off < 22528; off += 4096) *(uint4*)(smem + off) = z;
    }

    // staging groups: A g in [0,10): tm=g%5, kk=g/5, off g*1024
    //                 B g in [10,22): gb=g-10, tn=gb%6, kk=gb/6, off 10240+gb*1024
    const u16* gsrc[6]; int goff[6]; bool gval[6];
    #pragma unroll
    for (int j = 0; j < 6; ++j){
        int g = wave + j * 4;
        gval[j] = false; gsrc[j] = Ag; goff[j] = 0;
        if (g < 22){
            if (g < 10){
                int tm = g % 5, kk = g / 5;
                int row = tm * 16 + frow;
                gsrc[j] = Ag + (size_t)row * D_EMB + kk * 32 + q * 8;
                goff[j] = g * 1024;
                gval[j] = (row < 74);
            } else {
                int gb = g - 10;
                int tn = gb % 6, kk = gb / 6;
                int row = tn * 16 + frow;
                gsrc[j] = Bg + (size_t)row * D_EMB + kk * 32 + q * 8;
                goff[j] = 10240 + gb * 1024;
                gval[j] = (row < 82);
            }
        }
    }

    int wm = wave >> 1, wn = wave & 1;     // 2x2 wave grid over 5x6 MFMA tiles
    int nTm = wm ? 2 : 3;                  // m-tiles {wm, wm+2, wm+4} < 5
    f32x4 acc[3][3];
    #pragma unroll
    for (int aa = 0; aa < 3; ++aa)
        #pragma unroll
        for (int bb = 0; bb < 3; ++bb) acc[aa][bb] = (f32x4){0.f, 0.f, 0.f, 0.f};

    for (int c = 0; c < 16; ++c){          // K chunks of 64
        __syncthreads();                   // prev chunk's frag reads done
        #pragma unroll
        for (int j = 0; j < 6; ++j){
            if (gval[j]){
                __builtin_amdgcn_global_load_lds(
                    (const AS1 void*)(const void*)(gsrc[j] + c * 64),
                    (AS3 void*)(void*)(smem + goff[j] + lane * 16),
                    16, 0, 0);
            }
        }
        __syncthreads();                   // drains vmcnt -> data in LDS
        #pragma unroll
        for (int kk = 0; kk < 2; ++kk){
            bf16x8 bfr[3];
            #pragma unroll
            for (int ni = 0; ni < 3; ++ni){
                int tn = wn + ni * 2;
                bfr[ni] = *(const bf16x8*)(smem + 10240 + ((kk * 6 + tn) * 64 + lane) * 16);
            }
            #pragma unroll
            for (int mi = 0; mi < 3; ++mi){
                if (mi < nTm){
                    int tm = wm + mi * 2;
                    bf16x8 af = *(const bf16x8*)(smem + ((kk * 5 + tm) * 64 + lane) * 16);
                    #pragma unroll
                    for (int ni = 0; ni < 3; ++ni){
                        acc[mi][ni] = __builtin_amdgcn_mfma_f32_16x16x32_bf16(
                            af, bfr[ni], acc[mi][ni], 0, 0, 0);
                    }
                }
            }
        }
    }
    __syncthreads();                       // all frag reads done before overlay

    // C/D layout: col = lane&15 (B-row), row = (lane>>4)*4 + reg (A-row)
    #pragma unroll
    for (int mi = 0; mi < 3; ++mi){
        if (mi < nTm){
            int tm = wm + mi * 2;
            #pragma unroll
            for (int ni = 0; ni < 3; ++ni){
                int tn = wn + ni * 2;
                int col = tn * 16 + frow;
                int rbase = tm * 16 + q * 4;
                if (col < 82){
                    #pragma unroll
                    for (int g = 0; g < 4; ++g){
                        int rowc = rbase + g;
                        if (rowc < 74) Call[rowc * 85 + col] = acc[mi][ni][g];
                    }
                }
            }
        }
    }
    __syncthreads();                       // C complete; post phase is read-only on Call

    // ----- post-processing: one wave per (b,i) pair -----
    int pb = wave >> 1, pi = wave & 1;
    int bg = b0 + pb, ig = i0 + pi;
    const float* Sv = Call + (pb * 37) * 85 + pi * 41;  // S[r*85+l]; p[r]=S[r*85+40]; qv[l]=S[36*85+l]
    const u16* Lb_t2i = Lbi + (size_t)bg * 3072;        // [48][64] bf16, B[n][k]=L[k][n]
    const u16* Lb_i2t = Lbc + (size_t)ig * 3072;

    {   // row norms over words (lanes = regions); wave-private slice, no barrier.
        // 9x softmax scale folded in: rnb = 9/(||row||+eps).
        int r0 = (lane < 36) ? lane : 35;
        float s2 = 0.f;
        #pragma unroll
        for (int l = 0; l < 40; ++l){ float x = leaky(Sv[r0 * 85 + l]); s2 = fmaf(x, x, s2); }
        if (lane < 36) rnb[wave * 36 + lane] = 9.f / (sqrtf(s2) + 1e-8f);
    }
    {   // column norms over regions (lanes = words); cnb = 9/(||col||+eps)
        int l0 = (lane < 40) ? lane : 39;
        float s2 = 0.f;
        #pragma unroll
        for (int r = 0; r < 36; ++r){ float x = leaky(Sv[r * 85 + l0]); s2 = fmaf(x, x, s2); }
        if (lane < 40) cnb[wave * 40 + lane] = 9.f / (sqrtf(s2) + 1e-8f);
    }
    float base = Sv[36 * 85 + 40];

    // ---- t2i:  Y = U·L_img (M=40 words, K=36 regions pad 64, N=36 + num row)
    //      U[m][k] = exp(leaky(S[k][m])*rnb9[k]) built per-fragment on the fly
    //      (rn>0 => leaky(x)*rn == leaky(x*rn), so one mul before leaky);
    //      B-row n=36 carries p[k] -> Y[m][36] = num[m].
    float tsum;
    {
        f32x4 pacc[3][3];
        #pragma unroll
        for (int aa = 0; aa < 3; ++aa)
            #pragma unroll
            for (int bb = 0; bb < 3; ++bb) pacc[aa][bb] = (f32x4){0.f,0.f,0.f,0.f};
        #pragma unroll
        for (int kk = 0; kk < 2; ++kk){
            float rn[8];
            #pragma unroll
            for (int j = 0; j < 8; ++j){
                int k = kk * 32 + q * 8 + j;
                int kc = (k < 36) ? k : 35;                  // clamp: in-bounds reads
                rn[j] = (k < 36) ? rnb[wave * 36 + kc] : 0.f;
            }
            u32x4 pw;                                        // p-injection (B row 36)
            #pragma unroll
            for (int jj = 0; jj < 4; ++jj){
                int k0 = kk * 32 + q * 8 + jj * 2, k1 = k0 + 1;
                int c0 = (k0 < 36) ? k0 : 35, c1 = (k1 < 36) ? k1 : 35;
                float p0 = (k0 < 36) ? Sv[c0 * 85 + 40] : 0.f;
                float p1 = (k1 < 36) ? Sv[c1 * 85 + 40] : 0.f;
                pw[jj] = pack2(p0, p1);
            }
            bf16x8 afr[3];
            #pragma unroll
            for (int mt = 0; mt < 3; ++mt){
                int m = mt * 16 + frow;      // word col; m>=40 garbage, masked at reduce
                int mc = (m < 40) ? m : 39;                  // clamp: finite, written cols
                u32x4 aw;
                #pragma unroll
                for (int jj = 0; jj < 4; ++jj){
                    int k0 = kk * 32 + q * 8 + jj * 2, k1 = k0 + 1;
                    int c0 = (k0 < 36) ? k0 : 35, c1 = (k1 < 36) ? k1 : 35;
                    float e0 = __expf(leaky(Sv[c0 * 85 + mc] * rn[jj * 2]));
                    float e1 = __expf(leaky(Sv[c1 * 85 + mc] * rn[jj * 2 + 1]));
                    e0 = (k0 < 36) ? e0 : 0.f;
                    e1 = (k1 < 36) ? e1 : 0.f;
                    aw[jj] = pack2(e0, e1);
                }
                afr[mt] = __builtin_bit_cast(bf16x8, aw);
            }
            #pragma unroll
            for (int nt = 0; nt < 3; ++nt){
                bf16x8 bfr = *(const bf16x8*)(Lb_t2i + (nt * 16 + frow) * 64 + kk * 32 + q * 8);
                if (nt == 2 && frow == 4) bfr = __builtin_bit_cast(bf16x8, pw);
                #pragma unroll
                for (int mt = 0; mt < 3; ++mt)
                    pacc[mt][nt] = __builtin_amdgcn_mfma_f32_16x16x32_bf16(
                        afr[mt], bfr, pacc[mt][nt], 0, 0, 0);
            }
        }
        // zz[m] = sum_{n<36} Y[m][n]^2 ; num[m] = Y[m][36] (frow==4, nt=2)
        float w1 = w1t[ig];
        tsum = 0.f;
        #pragma unroll
        for (int mt = 0; mt < 3; ++mt){
            #pragma unroll
            for (int g = 0; g < 4; ++g){
                float sv = pacc[mt][0][g] * pacc[mt][0][g]
                         + pacc[mt][1][g] * pacc[mt][1][g];
                float t2 = pacc[mt][2][g] * pacc[mt][2][g];
                sv += (frow < 4) ? t2 : 0.f;            // n = 32+frow < 36
                sv += __shfl_xor(sv, 1); sv += __shfl_xor(sv, 2);
                sv += __shfl_xor(sv, 4); sv += __shfl_xor(sv, 8);
                float nm = __shfl(pacc[mt][2][g], (lane & 48) + 4);
                int m = mt * 16 + 4 * q + g;
                float sim = nm / fmaxf(w1 * sqrtf(sv), 1e-8f);
                tsum += (m < 40) ? sim : 0.f;           // mask garbage words
            }
        }
        tsum += __shfl_xor(tsum, 16);
        tsum += __shfl_xor(tsum, 32);
    }

    // ---- i2t:  Y = V·L_cap (M=36 regions, K=40 words pad 64, N=40 + num row)
    //      V[m][k] = exp(leaky(S[m][k])*cnb9[k]); B-row n=40 carries qv[k].
    float isum;
    {
        f32x4 pacc[3][3];
        #pragma unroll
        for (int aa = 0; aa < 3; ++aa)
            #pragma unroll
            for (int bb = 0; bb < 3; ++bb) pacc[aa][bb] = (f32x4){0.f,0.f,0.f,0.f};
        #pragma unroll
        for (int kk = 0; kk < 2; ++kk){
            float cn[8];
            #pragma unroll
            for (int j = 0; j < 8; ++j){
                int k = kk * 32 + q * 8 + j;
                int kc = (k < 40) ? k : 39;
                cn[j] = (k < 40) ? cnb[wave * 40 + kc] : 0.f;
            }
            u32x4 qw;                                        // qv-injection (B row 40)
            #pragma unroll
            for (int jj = 0; jj < 4; ++jj){
                int k0 = kk * 32 + q * 8 + jj * 2, k1 = k0 + 1;
                int c0 = (k0 < 40) ? k0 : 39, c1 = (k1 < 40) ? k1 : 39;
                float q0 = (k0 < 40) ? Sv[36 * 85 + c0] : 0.f;
                float q1 = (k1 < 40) ? Sv[36 * 85 + c1] : 0.f;
                qw[jj] = pack2(q0, q1);
            }
            bf16x8 afr[3];
            #pragma unroll
            for (int mt = 0; mt < 3; ++mt){
                int m = mt * 16 + frow;      // region row; m>=36 garbage, masked at reduce
                int mr = (m < 36) ? m : 35;                  // clamp: in-bounds reads
                u32x4 aw;
                #pragma unroll
                for (int jj = 0; jj < 4; ++jj){
                    int k0 = kk * 32 + q * 8 + jj * 2, k1 = k0 + 1;
                    int c0 = (k0 < 40) ? k0 : 39, c1 = (k1 < 40) ? k1 : 39;
                    float e0 = __expf(leaky(Sv[mr * 85 + c0] * cn[jj * 2]));
                    float e1 = __expf(leaky(Sv[mr * 85 + c1] * cn[jj * 2 + 1]));
                    e0 = (k0 < 40) ? e0 : 0.f;
                    e1 = (k1 < 40) ? e1 : 0.f;
                    aw[jj] = pack2(e0, e1);
                }
                afr[mt] = __builtin_bit_cast(bf16x8, aw);
            }
            #pragma unroll
            for (int nt = 0; nt < 3; ++nt){
                bf16x8 bfr = *(const bf16x8*)(Lb_i2t + (nt * 16 + frow) * 64 + kk * 32 + q * 8);
                if (nt == 2 && frow == 8) bfr = __builtin_bit_cast(bf16x8, qw);
                #pragma unroll
                for (int mt = 0; mt < 3; ++mt)
                    pacc[mt][nt] = __builtin_amdgcn_mfma_f32_16x16x32_bf16(
                        afr[mt], bfr, pacc[mt][nt], 0, 0, 0);
            }
        }
        float w1 = w1i[bg];
        isum = 0.f;
        #pragma unroll
        for (int mt = 0; mt < 3; ++mt){
            #pragma unroll
            for (int g = 0; g < 4; ++g){
                float sv = pacc[mt][0][g] * pacc[mt][0][g]
                         + pacc[mt][1][g] * pacc[mt][1][g];
                float t2 = pacc[mt][2][g] * pacc[mt][2][g];
                sv += (frow < 8) ? t2 : 0.f;            // n = 32+frow < 40
                sv += __shfl_xor(sv, 1); sv += __shfl_xor(sv, 2);
                sv += __shfl_xor(sv, 4); sv += __shfl_xor(sv, 8);
                float nm = __shfl(pacc[mt][2][g], (lane & 48) + 8);
                int m = mt * 16 + 4 * q + g;
                float sim = nm / fmaxf(w1 * sqrtf(sv), 1e-8f);
                isum += (m < 36) ? sim : 0.f;           // mask garbage regions
            }
        }
        isum += __shfl_xor(isum, 16);
        isum += __shfl_xor(isum, 32);
    }

    if (lane == 0)
        out[bg * 256 + ig] = tsum * (1.f / 40.f) + isum * (1.f / 36.f) + base;
}

// ---------------------------------------------------------------------------
extern "C" void kernel_launch(void* const* d_in, const int* in_sizes, int n_in,
                              void* d_out, int out_size, void* d_ws, size_t ws_size,
                              hipStream_t stream){
    const float* pool_img = (const float*)d_in[0];
    const float* img_emb  = (const float*)d_in[1];
    const float* pool_txt = (const float*)d_in[2];
    const float* cap_emb  = (const float*)d_in[3];
    float* out = (float*)d_out;

    char* ws = (char*)d_ws;                         // needs ~47 MB
    size_t o = 0;
    u16* imgw = (u16*)(ws + o);  o += (size_t)256 * 37 * 1024 * 2;
    u16* capw = (u16*)(ws + o);  o += (size_t)256 * 41 * 1024 * 2;
    float* G  = (float*)(ws + o); o += (size_t)256 * 36 * 36 * 4;
    float* H  = (float*)(ws + o); o += (size_t)256 * 40 * 40 * 4;
    float* w1i = (float*)(ws + o); o += 1024;
    float* w1t = (float*)(ws + o); o += 1024;
    u16* Lbi = (u16*)(ws + o); o += (size_t)256 * 48 * 64 * 2;   // chol(G)^T, bf16 [48][64]
    u16* Lbc = (u16*)(ws + o); o += (size_t)256 * 48 * 64 * 2;   // chol(H)^T

    pack_kernel<<<19968, 256, 0, stream>>>(pool_img, img_emb, pool_txt, cap_emb,
                                           imgw, capw, w1i, w1t);
    gram_kernel<<<512, 256, 0, stream>>>(imgw, capw, G, H);
    chol_kernel<<<128, 256, 0, stream>>>(G, H, Lbi, Lbc);
    fused_kernel<<<16384, 256, 0, stream>>>(imgw, capw, Lbi, Lbc, w1i, w1t, out);
}

// Round 8
// 722.095 us; speedup vs baseline: 1.1730x; 1.1173x over previous
//
#include <hip/hip_runtime.h>

typedef unsigned short u16;
typedef __attribute__((ext_vector_type(8))) short bf16x8;   // 8 bf16 (4 VGPRs)
typedef __attribute__((ext_vector_type(4))) float f32x4;
typedef __attribute__((ext_vector_type(2))) __fp16 h16x2;   // f16 pair (1 VGPR);
// NOTE: must be __fp16 (not _Float16) — clang's cvt_pkrtz/fdot2 builtins use
// the __fp16-based vector type and the two are not implicitly convertible.

#define D_EMB 1024
#define NBAT  256
#define AS1 __attribute__((address_space(1)))
#define AS3 __attribute__((address_space(3)))

__device__ __forceinline__ u16 f2bf(float f){
    unsigned int u = __float_as_uint(f);
    unsigned int r = (u + 0x7fffu + ((u >> 16) & 1u)) >> 16;  // RNE
    return (u16)r;
}
__device__ __forceinline__ float leaky(float x){ return x > 0.f ? x : 0.1f * x; }

// v_dot2_f32_f16: D = a.h0*b.h0 + a.h1*b.h1 + c (f16 mul, f32 accumulate,
// full VALU rate). Guarded fallback keeps compile safety (perf-only downgrade).
__device__ __forceinline__ float dot2h(h16x2 a, h16x2 b, float c){
#if __has_builtin(__builtin_amdgcn_fdot2)
    return __builtin_amdgcn_fdot2(a, b, c, false);
#else
    return fmaf((float)a[0], (float)b[0], fmaf((float)a[1], (float)b[1], c));
#endif
}

// ---------------------------------------------------------------------------
// Pack img_emb(+pool_img as row 36) and cap_emb(+pool_txt as row 40) to bf16,
// and (for pool rows) also emit the pool-vector L2 norm (norm_kernel folded).
// imgw: [256][37][1024] bf16, capw: [256][41][1024] bf16
// ---------------------------------------------------------------------------
__global__ void pack_kernel(const float* __restrict__ pool_img, const float* __restrict__ img_emb,
                            const float* __restrict__ pool_txt, const float* __restrict__ cap_emb,
                            u16* __restrict__ imgw, u16* __restrict__ capw,
                            float* __restrict__ w1i, float* __restrict__ w1t){
    __shared__ float red[256];
    int row = blockIdx.x;            // 0..19967
    const float* src; u16* dst;
    bool is_pool; float* wout;
    if (row < NBAT * 37){
        int e = row / 37, rr = row - e * 37;
        is_pool = (rr == 36);
        src = (rr < 36) ? (img_emb + ((size_t)e * 36 + rr) * D_EMB) : (pool_img + (size_t)e * D_EMB);
        dst = imgw + (size_t)row * D_EMB;
        wout = w1i + e;
    } else {
        int r2 = row - NBAT * 37;
        int e = r2 / 41, rr = r2 - e * 41;
        is_pool = (rr == 40);
        src = (rr < 40) ? (cap_emb + ((size_t)e * 40 + rr) * D_EMB) : (pool_txt + (size_t)e * D_EMB);
        dst = capw + (size_t)r2 * D_EMB;
        wout = w1t + e;
    }
    int t = threadIdx.x;             // 256 threads, 4 floats each
    float4 v = ((const float4*)src)[t];
    unsigned long long pk = (unsigned long long)f2bf(v.x)
        | ((unsigned long long)f2bf(v.y) << 16)
        | ((unsigned long long)f2bf(v.z) << 32)
        | ((unsigned long long)f2bf(v.w) << 48);
    *(unsigned long long*)(dst + (size_t)t * 4) = pk;
    if (is_pool){                    // block-uniform branch
        red[t] = v.x*v.x + v.y*v.y + v.z*v.z + v.w*v.w;
        __syncthreads();
        for (int off = 128; off > 0; off >>= 1){
            if (t < off) red[t] += red[t + off];
            __syncthreads();
        }
        if (t == 0) *wout = sqrtf(red[0]);
    }
}

// ---------------------------------------------------------------------------
// MFMA Gram kernel (reads packed bf16): blk<256 -> G[b]=E_img E_img^T (R=36),
// else H[b]=E_cap E_cap^T (R=40). Frag-order staging via global_load_lds.
// ---------------------------------------------------------------------------
__launch_bounds__(256, 2)
__global__ void gram_kernel(const u16* __restrict__ imgw, const u16* __restrict__ capw,
                            float* __restrict__ G, float* __restrict__ H){
    __shared__ __align__(16) char gsm[6144];    // 3 tiles x 2 kk x 64 lanes x 16B
    int blk = blockIdx.x;
    int tid = threadIdx.x, lane = tid & 63;
    int wave = __builtin_amdgcn_readfirstlane(tid >> 6);
    int frow = lane & 15, q = lane >> 4;

    const u16* E; float* Gout; int R;
    if (blk < NBAT){ E = imgw + (size_t)blk * 37 * D_EMB; Gout = G + (size_t)blk * 1296; R = 36; }
    else { int b = blk - NBAT; E = capw + (size_t)b * 41 * D_EMB; Gout = H + (size_t)b * 1600; R = 40; }

    {   // zero staging once (pad rows stay zero)
        uint4 z = {0u,0u,0u,0u};
        for (int off = tid * 16; off < 6144; off += 4096) *(uint4*)(gsm + off) = z;
    }

    // staging groups g = kk*3 + t, g in [0,6)
    const u16* gsrc[2]; int goff[2]; bool gval[2];
    #pragma unroll
    for (int j = 0; j < 2; ++j){
        int g = wave + j * 4;
        gval[j] = false; gsrc[j] = E; goff[j] = 0;
        if (g < 6){
            int kk = g / 3, t = g - kk * 3;
            int row = t * 16 + frow;
            gsrc[j] = E + (size_t)row * D_EMB + kk * 32 + q * 8;
            goff[j] = g * 1024;
            gval[j] = (row < R);
        }
    }

    int wm = wave >> 1, wn = wave & 1;
    int nTm = wm ? 1 : 2, nTn = wn ? 1 : 2;
    f32x4 acc[2][2];
    #pragma unroll
    for (int a = 0; a < 2; ++a)
        #pragma unroll
        for (int b = 0; b < 2; ++b) acc[a][b] = (f32x4){0.f,0.f,0.f,0.f};

    for (int c = 0; c < 16; ++c){
        __syncthreads();
        #pragma unroll
        for (int j = 0; j < 2; ++j){
            if (gval[j]){
                __builtin_amdgcn_global_load_lds(
                    (const AS1 void*)(const void*)(gsrc[j] + c * 64),
                    (AS3 void*)(void*)(gsm + goff[j] + lane * 16),
                    16, 0, 0);
            }
        }
        __syncthreads();
        #pragma unroll
        for (int kk = 0; kk < 2; ++kk){
            bf16x8 fA[2], fB[2];
            #pragma unroll
            for (int mi = 0; mi < 2; ++mi)
                if (mi < nTm) fA[mi] = *(const bf16x8*)(gsm + ((kk * 3 + (wm + mi * 2)) * 64 + lane) * 16);
            #pragma unroll
            for (int ni = 0; ni < 2; ++ni)
                if (ni < nTn) fB[ni] = *(const bf16x8*)(gsm + ((kk * 3 + (wn + ni * 2)) * 64 + lane) * 16);
            #pragma unroll
            for (int mi = 0; mi < 2; ++mi)
                if (mi < nTm)
                    #pragma unroll
                    for (int ni = 0; ni < 2; ++ni)
                        if (ni < nTn)
                            acc[mi][ni] = __builtin_amdgcn_mfma_f32_16x16x32_bf16(
                                fA[mi], fB[ni], acc[mi][ni], 0, 0, 0);
        }
    }

    #pragma unroll
    for (int mi = 0; mi < 2; ++mi){
        if (mi < nTm){
            int tm = wm + mi * 2;
            #pragma unroll
            for (int ni = 0; ni < 2; ++ni){
                if (ni < nTn){
                    int tn = wn + ni * 2;
                    int col = tn * 16 + frow;
                    if (col < R){
                        #pragma unroll
                        for (int g = 0; g < 4; ++g){
                            int row = tm * 16 + q * 4 + g;
                            if (row < R) Gout[row * R + col] = acc[mi][ni][g];
                        }
                    }
                }
            }
        }
    }
}

// ---------------------------------------------------------------------------
// Pack G/H rows to f16 pairs for v_dot2_f32_f16 consumption.
// Gh: [256][36][18] pairs, Hh: [256][40][20] pairs (rows have even length,
// pairs never straddle rows). |G| <= ~1300 fits f16 range easily.
// ---------------------------------------------------------------------------
__global__ void ghpack_kernel(const float* __restrict__ G, const float* __restrict__ H,
                              h16x2* __restrict__ Gh, h16x2* __restrict__ Hh){
    int id = blockIdx.x;             // 0..511
    int t = threadIdx.x;
    if (id < NBAT){
        const float* src = G + (size_t)id * 1296;
        h16x2* dst = Gh + (size_t)id * 648;
        for (int i = t; i < 648; i += 256)
            dst[i] = __builtin_amdgcn_cvt_pkrtz(src[2 * i], src[2 * i + 1]);
    } else {
        const float* src = H + (size_t)(id - NBAT) * 1600;
        h16x2* dst = Hh + (size_t)(id - NBAT) * 800;
        for (int i = t; i < 800; i += 256)
            dst[i] = __builtin_amdgcn_cvt_pkrtz(src[2 * i], src[2 * i + 1]);
    }
}

// ---------------------------------------------------------------------------
// Fused main kernel. One block = 2 images x 2 captions.
// GEMM phase: R0 structure exactly (best evidence: 712us; R6 falsified the
// K=32-pipeline alternative). Post phase: R0 scalar structure, but the
// quadratic forms u^T G u / v^T H v use v_dot2_f32_f16 against f16-packed
// G/H: 648/800 dot2 ops replace 630/780 unpack+fma pairs -> ~1400 fewer
// VALU issues per lane on the phase that drives VALUBusy=57%. Weights pack
// via v_cvt_pkrtz (1 inst). u dies before v is born (R0 register discipline,
// 48-arch fit at (256,5)). f16 on u AND G beats R0's bf16-u precision.
// ---------------------------------------------------------------------------
__launch_bounds__(256, 5)
__global__ void fused_kernel(const u16* __restrict__ imgw, const u16* __restrict__ capw,
                             const h16x2* __restrict__ Gh, const h16x2* __restrict__ Hh,
                             const float* __restrict__ w1i, const float* __restrict__ w1t,
                             float* __restrict__ out){
    __shared__ __align__(16) char smem[26624];
    float* Call = (float*)smem;                 // overlay after GEMM: [74][85]
    float* rnb  = (float*)(smem + 25160);       // [4][36]
    float* cnb  = (float*)(smem + 25736);       // [4][40]

    int tid  = threadIdx.x;
    int lane = tid & 63;
    int wave = __builtin_amdgcn_readfirstlane(tid >> 6);
    int frow = lane & 15, q = lane >> 4;

    int lin = blockIdx.x;
    int xcd = lin & 7;                   // XCD-aware swizzle (16384 % 8 == 0, bijective)
    int s   = lin >> 3;                  // 0..2047
    int b_t = (xcd << 4) | (s & 15);     // each XCD owns 16 b-tiles
    int i_t = s >> 4;                    // 0..127
    int b0 = b_t * 2, i0 = i_t * 2;
    const u16* Ag = imgw + (size_t)b0 * 37 * D_EMB;   // 74 rows
    const u16* Bg = capw + (size_t)i0 * 41 * D_EMB;   // 82 rows

    {   // zero staging region once (pad slots stay zero forever)
        uint4 z = {0u,0u,0u,0u};
        for (int off = tid * 16; off < 22528; off += 4096) *(uint4*)(smem + off) = z;
    }

    // staging groups: A g in [0,10): tm=g%5, kk=g/5, off g*1024
    //                 B g in [10,22): gb=g-10, tn=gb%6, kk=gb/6, off 10240+gb*1024
    const u16* gsrc[6]; int goff[6]; bool gval[6];
    #pragma unroll
    for (int j = 0; j < 6; ++j){
        int g = wave + j * 4;
        gval[j] = false; gsrc[j] = Ag; goff[j] = 0;
        if (g < 22){
            if (g < 10){
                int tm = g % 5, kk = g / 5;
                int row = tm * 16 + frow;
                gsrc[j] = Ag + (size_t)row * D_EMB + kk * 32 + q * 8;
                goff[j] = g * 1024;
                gval[j] = (row < 74);
            } else {
                int gb = g - 10;
                int tn = gb % 6, kk = gb / 6;
                int row = tn * 16 + frow;
                gsrc[j] = Bg + (size_t)row * D_EMB + kk * 32 + q * 8;
                goff[j] = 10240 + gb * 1024;
                gval[j] = (row < 82);
            }
        }
    }

    int wm = wave >> 1, wn = wave & 1;     // 2x2 wave grid over 5x6 MFMA tiles
    int nTm = wm ? 2 : 3;                  // m-tiles {wm, wm+2, wm+4} < 5
    f32x4 acc[3][3];
    #pragma unroll
    for (int aa = 0; aa < 3; ++aa)
        #pragma unroll
        for (int bb = 0; bb < 3; ++bb) acc[aa][bb] = (f32x4){0.f, 0.f, 0.f, 0.f};

    for (int c = 0; c < 16; ++c){          // K chunks of 64
        __syncthreads();                   // prev chunk's frag reads done
        #pragma unroll
        for (int j = 0; j < 6; ++j){
            if (gval[j]){
                __builtin_amdgcn_global_load_lds(
                    (const AS1 void*)(const void*)(gsrc[j] + c * 64),
                    (AS3 void*)(void*)(smem + goff[j] + lane * 16),
                    16, 0, 0);
            }
        }
        __syncthreads();                   // drains vmcnt -> data in LDS
        #pragma unroll
        for (int kk = 0; kk < 2; ++kk){
            bf16x8 bfr[3];
            #pragma unroll
            for (int ni = 0; ni < 3; ++ni){
                int tn = wn + ni * 2;
                bfr[ni] = *(const bf16x8*)(smem + 10240 + ((kk * 6 + tn) * 64 + lane) * 16);
            }
            #pragma unroll
            for (int mi = 0; mi < 3; ++mi){
                if (mi < nTm){
                    int tm = wm + mi * 2;
                    bf16x8 af = *(const bf16x8*)(smem + ((kk * 5 + tm) * 64 + lane) * 16);
                    #pragma unroll
                    for (int ni = 0; ni < 3; ++ni){
                        acc[mi][ni] = __builtin_amdgcn_mfma_f32_16x16x32_bf16(
                            af, bfr[ni], acc[mi][ni], 0, 0, 0);
                    }
                }
            }
        }
    }
    __syncthreads();                       // all frag reads done before overlay

    // C/D layout: col = lane&15 (B-row), row = (lane>>4)*4 + reg (A-row)
    #pragma unroll
    for (int mi = 0; mi < 3; ++mi){
        if (mi < nTm){
            int tm = wm + mi * 2;
            #pragma unroll
            for (int ni = 0; ni < 3; ++ni){
                int tn = wn + ni * 2;
                int col = tn * 16 + frow;
                int rbase = tm * 16 + q * 4;
                if (col < 82){
                    #pragma unroll
                    for (int g = 0; g < 4; ++g){
                        int rowc = rbase + g;
                        if (rowc < 74) Call[rowc * 85 + col] = acc[mi][ni][g];
                    }
                }
            }
        }
    }
    __syncthreads();

    // ----- post-processing: one wave per (b,i) pair -----
    int pb = wave >> 1, pi = wave & 1;
    int bg = b0 + pb, ig = i0 + pi;
    const float* Sv = Call + (pb * 37) * 85 + pi * 41;  // S[r*85+l]; p[r]=S[r*85+40]; qv[l]=S[36*85+l]
    const h16x2* Gp = Gh + (size_t)bg * 648;            // wave-uniform base
    const h16x2* Hp = Hh + (size_t)ig * 800;

    {   // row norms over words (lanes = regions); 9x softmax scale folded in
        int r0 = (lane < 36) ? lane : 35;
        float s2 = 0.f;
        #pragma unroll
        for (int l = 0; l < 40; ++l){ float x = leaky(Sv[r0 * 85 + l]); s2 = fmaf(x, x, s2); }
        if (lane < 36) rnb[wave * 36 + lane] = 9.f / (sqrtf(s2) + 1e-8f);
    }
    float t2i_sum;
    {   // lanes = words; u packed as 18 f16 pairs (cvt_pkrtz), dd cancels
        int lc = (lane < 40) ? lane : 39;
        h16x2 uh[18];
        float num = 0.f;
        #pragma unroll
        for (int r = 0; r < 36; r += 2){
            float e0 = __expf(leaky(Sv[r * 85 + lc] * rnb[wave * 36 + r]));
            float e1 = __expf(leaky(Sv[(r + 1) * 85 + lc] * rnb[wave * 36 + r + 1]));
            num = fmaf(e0, Sv[r * 85 + 40], fmaf(e1, Sv[(r + 1) * 85 + 40], num));
            uh[r >> 1] = __builtin_amdgcn_cvt_pkrtz(e0, e1);
        }
        float zz = 0.f;
        #pragma unroll
        for (int rr = 0; rr < 36; ++rr){
            float w = 0.f;
            #pragma unroll
            for (int j = 0; j < 18; ++j)
                w = dot2h(uh[j], Gp[rr * 18 + j], w);
            zz = fmaf((float)uh[rr >> 1][rr & 1], w, zz);
        }
        float w2s = sqrtf(fmaxf(zz, 0.f));
        float sim = num / fmaxf(w1t[ig] * w2s, 1e-8f);   // dd cancels in ratio
        sim = (lane < 40) ? sim : 0.f;
        #pragma unroll
        for (int off = 32; off > 0; off >>= 1) sim += __shfl_down(sim, off);
        t2i_sum = sim;
    }

    {   // column norms over regions (lanes = words); 9x folded
        int l0 = (lane < 40) ? lane : 39;
        float s2 = 0.f;
        #pragma unroll
        for (int r = 0; r < 36; ++r){ float x = leaky(Sv[r * 85 + l0]); s2 = fmaf(x, x, s2); }
        if (lane < 40) cnb[wave * 40 + lane] = 9.f / (sqrtf(s2) + 1e-8f);
    }
    float i2t_sum;
    {   // lanes = regions; v packed as 20 f16 pairs
        int rc = (lane < 36) ? lane : 35;
        h16x2 vh[20];
        float num = 0.f;
        #pragma unroll
        for (int l = 0; l < 40; l += 2){
            float e0 = __expf(leaky(Sv[rc * 85 + l] * cnb[wave * 40 + l]));
            float e1 = __expf(leaky(Sv[rc * 85 + l + 1] * cnb[wave * 40 + l + 1]));
            num = fmaf(e0, Sv[36 * 85 + l], fmaf(e1, Sv[36 * 85 + l + 1], num));
            vh[l >> 1] = __builtin_amdgcn_cvt_pkrtz(e0, e1);
        }
        float zz = 0.f;
        #pragma unroll
        for (int ll = 0; ll < 40; ++ll){
            float w = 0.f;
            #pragma unroll
            for (int j = 0; j < 20; ++j)
                w = dot2h(vh[j], Hp[ll * 20 + j], w);
            zz = fmaf((float)vh[ll >> 1][ll & 1], w, zz);
        }
        float w2s = sqrtf(fmaxf(zz, 0.f));
        float sim = num / fmaxf(w1i[bg] * w2s, 1e-8f);
        sim = (lane < 36) ? sim : 0.f;
        #pragma unroll
        for (int off = 32; off > 0; off >>= 1) sim += __shfl_down(sim, off);
        i2t_sum = sim;
    }

    if (lane == 0)
        out[bg * 256 + ig] = t2i_sum * (1.f / 40.f) + i2t_sum * (1.f / 36.f) + Sv[36 * 85 + 40];
}

// ---------------------------------------------------------------------------
extern "C" void kernel_launch(void* const* d_in, const int* in_sizes, int n_in,
                              void* d_out, int out_size, void* d_ws, size_t ws_size,
                              hipStream_t stream){
    const float* pool_img = (const float*)d_in[0];
    const float* img_emb  = (const float*)d_in[1];
    const float* pool_txt = (const float*)d_in[2];
    const float* cap_emb  = (const float*)d_in[3];
    float* out = (float*)d_out;

    char* ws = (char*)d_ws;                         // needs ~44 MB
    size_t o = 0;
    u16* imgw = (u16*)(ws + o);  o += (size_t)256 * 37 * 1024 * 2;
    u16* capw = (u16*)(ws + o);  o += (size_t)256 * 41 * 1024 * 2;
    float* G  = (float*)(ws + o); o += (size_t)256 * 36 * 36 * 4;
    float* H  = (float*)(ws + o); o += (size_t)256 * 40 * 40 * 4;
    float* w1i = (float*)(ws + o); o += 1024;
    float* w1t = (float*)(ws + o); o += 1024;
    h16x2* Gh = (h16x2*)(ws + o); o += (size_t)256 * 648 * 4;   // G as f16 pairs
    h16x2* Hh = (h16x2*)(ws + o); o += (size_t)256 * 800 * 4;   // H as f16 pairs

    pack_kernel<<<19968, 256, 0, stream>>>(pool_img, img_emb, pool_txt, cap_emb,
                                           imgw, capw, w1i, w1t);
    gram_kernel<<<512, 256, 0, stream>>>(imgw, capw, G, H);
    ghpack_kernel<<<512, 256, 0, stream>>>(G, H, Gh, Hh);
    fused_kernel<<<16384, 256, 0, stream>>>(imgw, capw, Gh, Hh, w1i, w1t, out);
}